// Round 2
// baseline (3178.570 us; speedup 1.0000x reference)
//
#include <hip/hip_runtime.h>
#include <math.h>

#define B_ 16
#define N_ 4096
#define D_ 64
#define M_ 1024
#define K_ 32
#define RTOT (B_*M_*K_)          // 524288 rows
#define EPSF 1e-5f

// ---------------- ws layout (float units) — total 2688256 floats = 10.75 MB
#define WT0_OFF   0              // [68*64]  = 4352
#define WT1_OFF   4352           // [64*64]  = 4096
#define WT2_OFF   8448           // [64*128] = 8192
#define ST_OFF    16640          // s0,q0,s1,q1 [64 each]; s2,q2 [128 each] = 512
#define BN_OFF    17152          // ab0[128] ab1[128] ab2[256] = 512
#define NXW_OFF   17664          // new_xyz f32 [16384*3]
#define KIDX_OFF  66816          // knn idx int [524288]
#define PK_OFF    591104         // packed bf16 (max,min) [16384*128] uint32

__device__ inline unsigned bf16u(float x) {
    unsigned u = __float_as_uint(x);
    return (u + 0x7FFFu + ((u >> 16) & 1u)) >> 16;   // RN-even
}

// ---------------- prep: zero stats, transpose weights ----------------
__global__ void prep_kernel(const float* __restrict__ W0, const float* __restrict__ W1,
                            const float* __restrict__ W2, float* __restrict__ ws) {
    int tid = threadIdx.x;
    float* wt0 = ws + WT0_OFF; float* wt1 = ws + WT1_OFF; float* wt2 = ws + WT2_OFF;
    float* st  = ws + ST_OFF;
    for (int i = tid; i < 512; i += 256) st[i] = 0.f;
    for (int i = tid; i < 68*64; i += 256) { int c = i >> 6, o = i & 63; wt0[i] = (c < 67) ? W0[o*67 + c] : 0.f; }
    for (int i = tid; i < 64*64; i += 256) { int c = i >> 6, o = i & 63; wt1[i] = W1[o*64 + c]; }
    for (int i = tid; i < 64*128; i += 256){ int c = i >> 7, o = i & 127; wt2[i] = W2[o*64 + c]; }
}

// ---------------- FPS: one block (1024 thr) per batch ----------------
__global__ __launch_bounds__(1024) void fps_kernel(const float* __restrict__ xyz,
                                                   float* __restrict__ out_newxyz,
                                                   float* __restrict__ out_fpsidx,
                                                   float* __restrict__ ws_newxyz) {
#pragma clang fp contract(off)
    __shared__ float sx[N_], sy[N_], sz[N_];
    __shared__ float redV[2][16];
    __shared__ int   redI[2][16];
    const int b = blockIdx.x;
    const int tid = threadIdx.x;
    const int lane = tid & 63, wave = tid >> 6;
    const float* xb = xyz + (size_t)b * N_ * 3;
    for (int i = tid; i < N_; i += 1024) {
        sx[i] = xb[i*3+0]; sy[i] = xb[i*3+1]; sz[i] = xb[i*3+2];
    }
    __syncthreads();
    float px[4], py[4], pz[4], dist[4];
#pragma unroll
    for (int j = 0; j < 4; ++j) {
        int p = tid + j*1024;
        px[j] = sx[p]; py[j] = sy[p]; pz[j] = sz[p];
        dist[j] = 3.4e38f;
    }
    int cur = N_/2;
    int myIdx = 0;
    for (int t = 0; t < M_; ++t) {
        if (tid == t) myIdx = cur;
        if (t == M_-1) break;
        float cx = sx[cur], cy = sy[cur], cz = sz[cur];
        float bv = -1.f; int bi = 0x7fffffff;
#pragma unroll
        for (int j = 0; j < 4; ++j) {
            int p = tid + j*1024;
            float dx = px[j]-cx, dy = py[j]-cy, dz = pz[j]-cz;
            float d = dx*dx + dy*dy; d = d + dz*dz;
            float dj = fminf(dist[j], d); dist[j] = dj;
            bool better = (dj > bv) || (dj == bv && p < bi);
            bv = better ? dj : bv; bi = better ? p : bi;
        }
#pragma unroll
        for (int off = 32; off > 0; off >>= 1) {
            float ov = __shfl_xor(bv, off);
            int   oi = __shfl_xor(bi, off);
            bool better = (ov > bv) || (ov == bv && oi < bi);
            bv = better ? ov : bv; bi = better ? oi : bi;
        }
        int buf = t & 1;
        if (lane == 0) { redV[buf][wave] = bv; redI[buf][wave] = bi; }
        __syncthreads();
        float v2 = -1.f; int i2 = 0x7fffffff;
        if (lane < 16) { v2 = redV[buf][lane]; i2 = redI[buf][lane]; }
#pragma unroll
        for (int off = 8; off > 0; off >>= 1) {
            float ov = __shfl_xor(v2, off);
            int   oi = __shfl_xor(i2, off);
            bool better = (ov > v2) || (ov == v2 && oi < i2);
            v2 = better ? ov : v2; i2 = better ? oi : i2;
        }
        cur = __shfl(i2, 0);
    }
    int c = myIdx;
    out_fpsidx[b*M_ + tid] = (float)c;
    float x = sx[c], y = sy[c], z = sz[c];
    size_t o3 = (size_t)(b*M_ + tid)*3;
    out_newxyz[o3+0] = x; out_newxyz[o3+1] = y; out_newxyz[o3+2] = z;
    ws_newxyz[o3+0] = x; ws_newxyz[o3+1] = y; ws_newxyz[o3+2] = z;
}

// ---------------- kNN: one wave per query ----------------
__global__ __launch_bounds__(256) void knn_kernel(const float* __restrict__ xyz,
                                                  const float* __restrict__ ws_newxyz,
                                                  int* __restrict__ knn_idx) {
#pragma clang fp contract(off)
    const int lane = threadIdx.x & 63;
    const int q = blockIdx.x * 4 + (threadIdx.x >> 6);
    const int b = q >> 10;
    const float* xb = xyz + (size_t)b * N_ * 3;
    float qx = ws_newxyz[q*3+0], qy = ws_newxyz[q*3+1], qz = ws_newxyz[q*3+2];
    float qq = qx*qx + qy*qy; qq = qq + qz*qz;
    float val[64];
    float lmV = 3.4e38f; int lmK = 0;
#pragma unroll
    for (int k = 0; k < 64; ++k) {
        int n = (k<<6) + lane;
        float x = xb[n*3+0], y = xb[n*3+1], z = xb[n*3+2];
        float pp = x*x + y*y; pp = pp + z*z;
        float dot = qx*x + qy*y; dot = dot + qz*z;
        float d = (qq + pp) - 2.0f*dot;
        val[k] = d;
        if (d < lmV) { lmV = d; lmK = k; }
    }
    unsigned int myOut = 0;
    for (int r = 0; r < 32; ++r) {
        unsigned int u = __float_as_uint(lmV);
        u = (u & 0x80000000u) ? ~u : (u | 0x80000000u);   // orderable key
        unsigned long long pk = ((unsigned long long)u << 32) | (unsigned)(lane + (lmK<<6));
#pragma unroll
        for (int off = 32; off > 0; off >>= 1) {
            unsigned long long o = __shfl_xor(pk, off);
            pk = (o < pk) ? o : pk;
        }
        unsigned g = (unsigned)pk;
        if (lane == r) myOut = g;
        if (lane == (int)(g & 63u)) {
            int kk = (int)(g >> 6);
#pragma unroll
            for (int k = 0; k < 64; ++k) if (k == kk) val[k] = 3.4e38f;
            lmV = 3.4e38f; lmK = 0;
#pragma unroll
            for (int k = 0; k < 64; ++k) if (val[k] < lmV) { lmV = val[k]; lmK = k; }
        }
    }
    if (lane < 32) knn_idx[q*32 + lane] = (int)myOut;
}

// ---------------- recompute MLP pass, depth = how many layers computed ----
// 64-row tile per block, 256 threads, 4x4 outputs per thread.
// DEPTH==1: stats for layer0.  DEPTH==2: L0+bn0+relu, stats for layer1.
// DEPTH==3: L0,L1 recomputed, L2 stats + per-group bf16-packed max/min.
template<int DEPTH>
__global__ __launch_bounds__(256) void mlp_pass(
    const float* __restrict__ xyz, const float* __restrict__ points,
    const float* __restrict__ nxw, const int* __restrict__ kidx,
    const float* __restrict__ wt0, const float* __restrict__ wt1,
    const float* __restrict__ wt2,
    const float* __restrict__ cb0, const float* __restrict__ cb1,
    const float* __restrict__ cb2,
    const float* __restrict__ bnab0, const float* __restrict__ bnab1,
    float* __restrict__ statS, float* __restrict__ statQ,
    unsigned int* __restrict__ packed)
{
    __shared__ float Xs[64*68];
    __shared__ float Wb[68*64];
    __shared__ float Gb[(DEPTH>=2) ? 64*64 : 1];
    __shared__ float sAcc[128], qAcc[128];
    __shared__ float mxs[(DEPTH==3) ? 16*64 : 1];
    __shared__ float mns[(DEPTH==3) ? 16*64 : 1];
    const int tid = threadIdx.x;
    const int r0 = blockIdx.x * 64;
    const int tx = tid & 15, ty = tid >> 4;

    // gather X0 tile [64 rows x 68 cols]
    for (int i = tid; i < 64*68; i += 256) {
        int r = i / 68, c = i - r*68;
        int gr = r0 + r;
        int q = gr >> 5;
        int n = kidx[gr];
        int bb = q >> 10;
        float v;
        if (c < 3)       v = xyz[((size_t)(bb*N_ + n))*3 + c] - nxw[q*3 + c];
        else if (c < 67) v = points[((size_t)(bb*N_ + n))*64 + (c-3)];
        else             v = 0.f;
        Xs[i] = v;
    }
    for (int i = tid; i < 68*64; i += 256) Wb[i] = wt0[i];
    if (tid < 128) { sAcc[tid] = 0.f; qAcc[tid] = 0.f; }
    __syncthreads();

    // ---- layer 0 GEMM ----
    float acc[4][4];
#pragma unroll
    for (int j = 0; j < 4; ++j) {
        float bv = cb0[tx*4+j];
#pragma unroll
        for (int i = 0; i < 4; ++i) acc[i][j] = bv;
    }
#pragma unroll 4
    for (int c = 0; c < 68; ++c) {
        float xa[4];
#pragma unroll
        for (int i = 0; i < 4; ++i) xa[i] = Xs[(ty*4+i)*68 + c];
        float4 w4 = *(const float4*)(Wb + c*64 + tx*4);
        float wb4[4] = {w4.x, w4.y, w4.z, w4.w};
#pragma unroll
        for (int i = 0; i < 4; ++i)
#pragma unroll
            for (int j = 0; j < 4; ++j) acc[i][j] = fmaf(xa[i], wb4[j], acc[i][j]);
    }

    if constexpr (DEPTH == 1) {
        float s4[4] = {0,0,0,0}, q4[4] = {0,0,0,0};
#pragma unroll
        for (int i = 0; i < 4; ++i)
#pragma unroll
            for (int j = 0; j < 4; ++j) { s4[j] += acc[i][j]; q4[j] += acc[i][j]*acc[i][j]; }
#pragma unroll
        for (int j = 0; j < 4; ++j) {
            atomicAdd(&sAcc[tx*4+j], s4[j]);
            atomicAdd(&qAcc[tx*4+j], q4[j]);
        }
        __syncthreads();
        if (tid < 64) { atomicAdd(statS + tid, sAcc[tid]); atomicAdd(statQ + tid, qAcc[tid]); }
        return;
    } else {
        // bn0 + relu
#pragma unroll
        for (int j = 0; j < 4; ++j) {
            float a = bnab0[tx*4+j], sh = bnab0[64 + tx*4+j];
#pragma unroll
            for (int i = 0; i < 4; ++i) acc[i][j] = fmaxf(fmaf(a, acc[i][j], sh), 0.f);
        }
        __syncthreads();   // everyone done reading Wb
#pragma unroll
        for (int i = 0; i < 4; ++i)
#pragma unroll
            for (int j = 0; j < 4; ++j) Gb[(ty*4+i)*64 + tx*4+j] = acc[i][j];
        for (int i = tid; i < 64*64; i += 256) Wb[i] = wt1[i];
        __syncthreads();

        // ---- layer 1 GEMM ----
        float acc2[4][4];
#pragma unroll
        for (int j = 0; j < 4; ++j) {
            float bv = cb1[tx*4+j];
#pragma unroll
            for (int i = 0; i < 4; ++i) acc2[i][j] = bv;
        }
#pragma unroll 4
        for (int c = 0; c < 64; ++c) {
            float xa[4];
#pragma unroll
            for (int i = 0; i < 4; ++i) xa[i] = Gb[(ty*4+i)*64 + c];
            float4 w4 = *(const float4*)(Wb + c*64 + tx*4);
            float wb4[4] = {w4.x, w4.y, w4.z, w4.w};
#pragma unroll
            for (int i = 0; i < 4; ++i)
#pragma unroll
                for (int j = 0; j < 4; ++j) acc2[i][j] = fmaf(xa[i], wb4[j], acc2[i][j]);
        }

        if constexpr (DEPTH == 2) {
            float s4[4] = {0,0,0,0}, q4[4] = {0,0,0,0};
#pragma unroll
            for (int i = 0; i < 4; ++i)
#pragma unroll
                for (int j = 0; j < 4; ++j) { s4[j] += acc2[i][j]; q4[j] += acc2[i][j]*acc2[i][j]; }
#pragma unroll
            for (int j = 0; j < 4; ++j) {
                atomicAdd(&sAcc[tx*4+j], s4[j]);
                atomicAdd(&qAcc[tx*4+j], q4[j]);
            }
            __syncthreads();
            if (tid < 64) { atomicAdd(statS + tid, sAcc[tid]); atomicAdd(statQ + tid, qAcc[tid]); }
            return;
        } else {
            // bn1 + relu
#pragma unroll
            for (int j = 0; j < 4; ++j) {
                float a = bnab1[tx*4+j], sh = bnab1[64 + tx*4+j];
#pragma unroll
                for (int i = 0; i < 4; ++i) acc2[i][j] = fmaxf(fmaf(a, acc2[i][j], sh), 0.f);
            }
            __syncthreads();   // everyone done reading Gb & Wb
#pragma unroll
            for (int i = 0; i < 4; ++i)
#pragma unroll
                for (int j = 0; j < 4; ++j) Gb[(ty*4+i)*64 + tx*4+j] = acc2[i][j];
            for (int i = tid; i < 64*64; i += 256) Wb[i] = wt2[(i>>6)*128 + (i&63)];
            __syncthreads();

            // ---- layer 2 GEMM, 2 halves of 64 output cols ----
            for (int h = 0; h < 2; ++h) {
                float acc3[4][4];
#pragma unroll
                for (int j = 0; j < 4; ++j) {
                    float bv = cb2[h*64 + tx*4+j];
#pragma unroll
                    for (int i = 0; i < 4; ++i) acc3[i][j] = bv;
                }
#pragma unroll 4
                for (int c = 0; c < 64; ++c) {
                    float xa[4];
#pragma unroll
                    for (int i = 0; i < 4; ++i) xa[i] = Gb[(ty*4+i)*64 + c];
                    float4 w4 = *(const float4*)(Wb + c*64 + tx*4);
                    float wb4[4] = {w4.x, w4.y, w4.z, w4.w};
#pragma unroll
                    for (int i = 0; i < 4; ++i)
#pragma unroll
                        for (int j = 0; j < 4; ++j) acc3[i][j] = fmaf(xa[i], wb4[j], acc3[i][j]);
                }
                float s4[4] = {0,0,0,0}, q4[4] = {0,0,0,0};
#pragma unroll
                for (int i = 0; i < 4; ++i)
#pragma unroll
                    for (int j = 0; j < 4; ++j) { s4[j] += acc3[i][j]; q4[j] += acc3[i][j]*acc3[i][j]; }
#pragma unroll
                for (int j = 0; j < 4; ++j) {
                    atomicAdd(&sAcc[h*64 + tx*4+j], s4[j]);
                    atomicAdd(&qAcc[h*64 + tx*4+j], q4[j]);
                }
#pragma unroll
                for (int j = 0; j < 4; ++j) {
                    float mx = fmaxf(fmaxf(acc3[0][j], acc3[1][j]), fmaxf(acc3[2][j], acc3[3][j]));
                    float mn = fminf(fminf(acc3[0][j], acc3[1][j]), fminf(acc3[2][j], acc3[3][j]));
                    mxs[ty*64 + tx*4+j] = mx;
                    mns[ty*64 + tx*4+j] = mn;
                }
                __syncthreads();
                if (tid < 128) {
                    int ql = tid >> 6, c = tid & 63;
                    float mx = mxs[(ql*8)*64 + c], mn = mns[(ql*8)*64 + c];
#pragma unroll
                    for (int w = 1; w < 8; ++w) {
                        mx = fmaxf(mx, mxs[(ql*8+w)*64 + c]);
                        mn = fminf(mn, mns[(ql*8+w)*64 + c]);
                    }
                    unsigned pk = (bf16u(mx) << 16) | bf16u(mn);
                    packed[(size_t)(blockIdx.x*2 + ql)*128 + h*64 + c] = pk;
                }
                if (h == 0) {
                    __syncthreads();   // mxs reads done; Wb reads done
                    for (int i = tid; i < 64*64; i += 256) Wb[i] = wt2[(i>>6)*128 + 64 + (i&63)];
                    __syncthreads();
                }
            }
            __syncthreads();
            if (tid < 128) { atomicAdd(statS + tid, sAcc[tid]); atomicAdd(statQ + tid, qAcc[tid]); }
        }
    }
}

// ---------------- BN finalize ----------------
template<int COUT>
__global__ void bn_finalize(const float* __restrict__ stat_s, const float* __restrict__ stat_q,
                            const float* __restrict__ gamma, const float* __restrict__ beta,
                            float* __restrict__ bnab) {
    int c = threadIdx.x;
    if (c < COUT) {
        const float inv_n = 1.f / (float)RTOT;
        float mu  = stat_s[c] * inv_n;
        float var = stat_q[c] * inv_n - mu*mu;
        float inv = 1.f / sqrtf(var + EPSF);
        float a = gamma[c] * inv;
        bnab[c] = a;
        bnab[COUT + c] = beta[c] - mu * a;
    }
}

// ---------------- final: BN2+ReLU on pooled extrema ----------------
__global__ __launch_bounds__(256) void final_out(const unsigned int* __restrict__ packed,
                                                 const float* __restrict__ bnab2,
                                                 float* __restrict__ out_np) {
    int idx = blockIdx.x*256 + threadIdx.x;
    int c = idx & 127;
    float a = bnab2[c], sh = bnab2[128 + c];
    unsigned p = packed[idx];
    float mx = __uint_as_float(p & 0xFFFF0000u);
    float mn = __uint_as_float(p << 16);
    float x = (a >= 0.f) ? mx : mn;
    out_np[idx] = fmaxf(fmaf(a, x, sh), 0.f);
}

extern "C" void kernel_launch(void* const* d_in, const int* in_sizes, int n_in,
                              void* d_out, int out_size, void* d_ws, size_t ws_size,
                              hipStream_t stream) {
    const float* xyz    = (const float*)d_in[0];
    const float* points = (const float*)d_in[1];
    const float* W0 = (const float*)d_in[2];
    const float* b0 = (const float*)d_in[3];
    const float* g0 = (const float*)d_in[4];
    const float* be0= (const float*)d_in[5];
    const float* W1 = (const float*)d_in[6];
    const float* b1 = (const float*)d_in[7];
    const float* g1 = (const float*)d_in[8];
    const float* be1= (const float*)d_in[9];
    const float* W2 = (const float*)d_in[10];
    const float* b2 = (const float*)d_in[11];
    const float* g2 = (const float*)d_in[12];
    const float* be2= (const float*)d_in[13];

    float* ws  = (float*)d_ws;
    float* out = (float*)d_out;
    float* out_newxyz = out;                        // 49152
    float* out_np     = out + 49152;                // 2097152
    float* out_fpsidx = out + 49152 + 2097152;      // 16384

    float* wt0 = ws + WT0_OFF; float* wt1 = ws + WT1_OFF; float* wt2 = ws + WT2_OFF;
    float* s0 = ws + ST_OFF;        float* q0 = s0 + 64;
    float* s1 = q0 + 64;            float* q1 = s1 + 64;
    float* s2 = q1 + 64;            float* q2 = s2 + 128;
    float* bnab0 = ws + BN_OFF;     float* bnab1 = bnab0 + 128;  float* bnab2 = bnab1 + 128;
    float* nxw   = ws + NXW_OFF;
    int*   kidx  = (int*)(ws + KIDX_OFF);
    unsigned int* packed = (unsigned int*)(ws + PK_OFF);

    prep_kernel<<<1, 256, 0, stream>>>(W0, W1, W2, ws);
    fps_kernel<<<B_, 1024, 0, stream>>>(xyz, out_newxyz, out_fpsidx, nxw);
    knn_kernel<<<(B_*M_)/4, 256, 0, stream>>>(xyz, nxw, kidx);

    mlp_pass<1><<<RTOT/64, 256, 0, stream>>>(xyz, points, nxw, kidx, wt0, wt1, wt2,
        b0, b1, b2, nullptr, nullptr, s0, q0, nullptr);
    bn_finalize<64><<<1, 64, 0, stream>>>(s0, q0, g0, be0, bnab0);

    mlp_pass<2><<<RTOT/64, 256, 0, stream>>>(xyz, points, nxw, kidx, wt0, wt1, wt2,
        b0, b1, b2, bnab0, nullptr, s1, q1, nullptr);
    bn_finalize<64><<<1, 64, 0, stream>>>(s1, q1, g1, be1, bnab1);

    mlp_pass<3><<<RTOT/64, 256, 0, stream>>>(xyz, points, nxw, kidx, wt0, wt1, wt2,
        b0, b1, b2, bnab0, bnab1, s2, q2, packed);
    bn_finalize<128><<<1, 128, 0, stream>>>(s2, q2, g2, be2, bnab2);

    final_out<<<(B_*M_*128)/256, 256, 0, stream>>>(packed, bnab2, out_np);
}

// Round 3
// 2442.853 us; speedup vs baseline: 1.3012x; 1.3012x over previous
//
#include <hip/hip_runtime.h>
#include <math.h>

#define B_ 16
#define N_ 4096
#define D_ 64
#define M_ 1024
#define K_ 32
#define RTOT (B_*M_*K_)          // 524288 rows
#define EPSF 1e-5f

// ---------------- ws layout (float units) — total 2688256 floats = 10.75 MB
#define WT0_OFF   0              // [68*64]  = 4352
#define WT1_OFF   4352           // [64*64]  = 4096
#define WT2_OFF   8448           // [64*128] = 8192
#define ST_OFF    16640          // s0,q0,s1,q1 [64 each]; s2,q2 [128 each] = 512
#define BN_OFF    17152          // ab0[128] ab1[128] ab2[256] = 512
#define NXW_OFF   17664          // new_xyz f32 [16384*3]
#define KIDX_OFF  66816          // knn idx int [524288]
#define PK_OFF    591104         // packed bf16 (max,min) [16384*128] uint32

__device__ inline unsigned bf16u(float x) {
    unsigned u = __float_as_uint(x);
    return (u + 0x7FFFu + ((u >> 16) & 1u)) >> 16;   // RN-even
}

// ---------------- prep: zero stats, transpose weights ----------------
__global__ void prep_kernel(const float* __restrict__ W0, const float* __restrict__ W1,
                            const float* __restrict__ W2, float* __restrict__ ws) {
    int tid = threadIdx.x;
    float* wt0 = ws + WT0_OFF; float* wt1 = ws + WT1_OFF; float* wt2 = ws + WT2_OFF;
    float* st  = ws + ST_OFF;
    for (int i = tid; i < 512; i += 256) st[i] = 0.f;
    for (int i = tid; i < 68*64; i += 256) { int c = i >> 6, o = i & 63; wt0[i] = (c < 67) ? W0[o*67 + c] : 0.f; }
    for (int i = tid; i < 64*64; i += 256) { int c = i >> 6, o = i & 63; wt1[i] = W1[o*64 + c]; }
    for (int i = tid; i < 64*128; i += 256){ int c = i >> 7, o = i & 127; wt2[i] = W2[o*64 + c]; }
}

// ---------------- FPS v2: 256 thr/block, packed-u64 DPP reduce ----------------
// Lane owns 16 CONTIGUOUS points [tid*16, tid*16+16) in registers.
// Per step: local min-update + local argmax, then single packed u64 max-reduce:
//   key = (dist_bits << 32) | ~gidx   (dist>=0 so bits are order-preserving;
//   ~gidx makes u64-max pick the LOWEST index on value ties = np.argmax).
// Row levels (1,2,4,8) via DPP row_ror (VALU pipe); 16/32 via shfl_xor; one
// barrier; every lane max-reduces the 4 wave keys itself (no 2nd shuffle phase).
#define ROR_MAX(kvar, CTRL) do {                                                   \
    unsigned _lo = (unsigned)(kvar), _hi = (unsigned)((kvar) >> 32);               \
    unsigned _rl = (unsigned)__builtin_amdgcn_update_dpp((int)_lo, (int)_lo, CTRL, 0xF, 0xF, false); \
    unsigned _rh = (unsigned)__builtin_amdgcn_update_dpp((int)_hi, (int)_hi, CTRL, 0xF, 0xF, false); \
    unsigned long long _o = ((unsigned long long)_rh << 32) | _rl;                 \
    if (_o > (kvar)) (kvar) = _o;                                                  \
} while (0)

__global__ __launch_bounds__(256) void fps_kernel(const float* __restrict__ xyz,
                                                  float* __restrict__ out_newxyz,
                                                  float* __restrict__ out_fpsidx,
                                                  float* __restrict__ ws_newxyz) {
#pragma clang fp contract(off)
    __shared__ float sx[N_], sy[N_], sz[N_];
    __shared__ int   selidx[M_];
    __shared__ unsigned long long red[2][4];
    const int b = blockIdx.x;
    const int tid = threadIdx.x;
    const int lane = tid & 63, wave = tid >> 6;
    const float* xb = xyz + (size_t)b * N_ * 3;
    for (int i = tid; i < N_; i += 256) {
        sx[i] = xb[i*3+0]; sy[i] = xb[i*3+1]; sz[i] = xb[i*3+2];
    }
    __syncthreads();
    float px[16], py[16], pz[16], dist[16];
#pragma unroll
    for (int j = 0; j < 16; ++j) {
        int p = (tid << 4) + j;
        px[j] = sx[p]; py[j] = sy[p]; pz[j] = sz[p];
        dist[j] = 3.4e38f;
    }
    int cur = N_/2;
    for (int t = 0; t < M_; ++t) {
        if (tid == (t & 255)) selidx[t] = cur;
        if (t == M_-1) break;
        float cx = sx[cur], cy = sy[cur], cz = sz[cur];
        float bm = -1.f; int bj = 0;
#pragma unroll
        for (int j = 0; j < 16; ++j) {
            float dx = px[j]-cx, dy = py[j]-cy, dz = pz[j]-cz;
            float a = dx*dx, b2 = dy*dy, c2 = dz*dz;
            float d = (a + b2) + c2;                       // matches np order
            float nd = fminf(dist[j], d); dist[j] = nd;
            bool better = nd > bm;                         // strict: first j wins ties
            bm = better ? nd : bm; bj = better ? j : bj;
        }
        int gidx = (tid << 4) + bj;
        unsigned long long key =
            ((unsigned long long)__float_as_uint(bm) << 32) | (unsigned)(~gidx);
        ROR_MAX(key, 0x121);   // row_ror:1
        ROR_MAX(key, 0x122);   // row_ror:2
        ROR_MAX(key, 0x124);   // row_ror:4
        ROR_MAX(key, 0x128);   // row_ror:8
        { unsigned long long o = __shfl_xor(key, 16); if (o > key) key = o; }
        { unsigned long long o = __shfl_xor(key, 32); if (o > key) key = o; }
        int buf = t & 1;
        if (lane == 0) red[buf][wave] = key;
        __syncthreads();
        unsigned long long k0 = red[buf][0], k1 = red[buf][1];
        unsigned long long k2 = red[buf][2], k3 = red[buf][3];
        unsigned long long m01 = (k0 > k1) ? k0 : k1;
        unsigned long long m23 = (k2 > k3) ? k2 : k3;
        unsigned long long m   = (m01 > m23) ? m01 : m23;
        cur = (int)((~(unsigned)m) & (N_-1));
    }
    __syncthreads();
    for (int i = tid; i < M_; i += 256) {
        int c = selidx[i];
        out_fpsidx[b*M_ + i] = (float)c;
        float x = sx[c], y = sy[c], z = sz[c];
        size_t o3 = (size_t)(b*M_ + i)*3;
        out_newxyz[o3+0] = x; out_newxyz[o3+1] = y; out_newxyz[o3+2] = z;
        ws_newxyz[o3+0] = x;  ws_newxyz[o3+1] = y;  ws_newxyz[o3+2] = z;
    }
}

// ---------------- kNN: one wave per query ----------------
__global__ __launch_bounds__(256) void knn_kernel(const float* __restrict__ xyz,
                                                  const float* __restrict__ ws_newxyz,
                                                  int* __restrict__ knn_idx) {
#pragma clang fp contract(off)
    const int lane = threadIdx.x & 63;
    const int q = blockIdx.x * 4 + (threadIdx.x >> 6);
    const int b = q >> 10;
    const float* xb = xyz + (size_t)b * N_ * 3;
    float qx = ws_newxyz[q*3+0], qy = ws_newxyz[q*3+1], qz = ws_newxyz[q*3+2];
    float qq = qx*qx + qy*qy; qq = qq + qz*qz;
    float val[64];
    float lmV = 3.4e38f; int lmK = 0;
#pragma unroll
    for (int k = 0; k < 64; ++k) {
        int n = (k<<6) + lane;
        float x = xb[n*3+0], y = xb[n*3+1], z = xb[n*3+2];
        float pp = x*x + y*y; pp = pp + z*z;
        float dot = qx*x + qy*y; dot = dot + qz*z;
        float d = (qq + pp) - 2.0f*dot;
        val[k] = d;
        if (d < lmV) { lmV = d; lmK = k; }
    }
    unsigned int myOut = 0;
    for (int r = 0; r < 32; ++r) {
        unsigned int u = __float_as_uint(lmV);
        u = (u & 0x80000000u) ? ~u : (u | 0x80000000u);   // orderable key
        unsigned long long pk = ((unsigned long long)u << 32) | (unsigned)(lane + (lmK<<6));
#pragma unroll
        for (int off = 32; off > 0; off >>= 1) {
            unsigned long long o = __shfl_xor(pk, off);
            pk = (o < pk) ? o : pk;
        }
        unsigned g = (unsigned)pk;
        if (lane == r) myOut = g;
        if (lane == (int)(g & 63u)) {
            int kk = (int)(g >> 6);
#pragma unroll
            for (int k = 0; k < 64; ++k) if (k == kk) val[k] = 3.4e38f;
            lmV = 3.4e38f; lmK = 0;
#pragma unroll
            for (int k = 0; k < 64; ++k) if (val[k] < lmV) { lmV = val[k]; lmK = k; }
        }
    }
    if (lane < 32) knn_idx[q*32 + lane] = (int)myOut;
}

// ---------------- recompute MLP pass, depth = how many layers computed ----
// 64-row tile per block, 256 threads, 4x4 outputs per thread.
// DEPTH==1: stats for layer0.  DEPTH==2: L0+bn0+relu, stats for layer1.
// DEPTH==3: L0,L1 recomputed, L2 stats + per-group bf16-packed max/min.
template<int DEPTH>
__global__ __launch_bounds__(256) void mlp_pass(
    const float* __restrict__ xyz, const float* __restrict__ points,
    const float* __restrict__ nxw, const int* __restrict__ kidx,
    const float* __restrict__ wt0, const float* __restrict__ wt1,
    const float* __restrict__ wt2,
    const float* __restrict__ cb0, const float* __restrict__ cb1,
    const float* __restrict__ cb2,
    const float* __restrict__ bnab0, const float* __restrict__ bnab1,
    float* __restrict__ statS, float* __restrict__ statQ,
    unsigned int* __restrict__ packed)
{
    __shared__ float Xs[64*68];
    __shared__ float Wb[68*64];
    __shared__ float Gb[(DEPTH>=2) ? 64*64 : 1];
    __shared__ float sAcc[128], qAcc[128];
    __shared__ float mxs[(DEPTH==3) ? 16*64 : 1];
    __shared__ float mns[(DEPTH==3) ? 16*64 : 1];
    const int tid = threadIdx.x;
    const int r0 = blockIdx.x * 64;
    const int tx = tid & 15, ty = tid >> 4;

    // gather X0 tile [64 rows x 68 cols]
    for (int i = tid; i < 64*68; i += 256) {
        int r = i / 68, c = i - r*68;
        int gr = r0 + r;
        int q = gr >> 5;
        int n = kidx[gr];
        int bb = q >> 10;
        float v;
        if (c < 3)       v = xyz[((size_t)(bb*N_ + n))*3 + c] - nxw[q*3 + c];
        else if (c < 67) v = points[((size_t)(bb*N_ + n))*64 + (c-3)];
        else             v = 0.f;
        Xs[i] = v;
    }
    for (int i = tid; i < 68*64; i += 256) Wb[i] = wt0[i];
    if (tid < 128) { sAcc[tid] = 0.f; qAcc[tid] = 0.f; }
    __syncthreads();

    // ---- layer 0 GEMM ----
    float acc[4][4];
#pragma unroll
    for (int j = 0; j < 4; ++j) {
        float bv = cb0[tx*4+j];
#pragma unroll
        for (int i = 0; i < 4; ++i) acc[i][j] = bv;
    }
#pragma unroll 4
    for (int c = 0; c < 68; ++c) {
        float xa[4];
#pragma unroll
        for (int i = 0; i < 4; ++i) xa[i] = Xs[(ty*4+i)*68 + c];
        float4 w4 = *(const float4*)(Wb + c*64 + tx*4);
        float wb4[4] = {w4.x, w4.y, w4.z, w4.w};
#pragma unroll
        for (int i = 0; i < 4; ++i)
#pragma unroll
            for (int j = 0; j < 4; ++j) acc[i][j] = fmaf(xa[i], wb4[j], acc[i][j]);
    }

    if constexpr (DEPTH == 1) {
        float s4[4] = {0,0,0,0}, q4[4] = {0,0,0,0};
#pragma unroll
        for (int i = 0; i < 4; ++i)
#pragma unroll
            for (int j = 0; j < 4; ++j) { s4[j] += acc[i][j]; q4[j] += acc[i][j]*acc[i][j]; }
#pragma unroll
        for (int j = 0; j < 4; ++j) {
            atomicAdd(&sAcc[tx*4+j], s4[j]);
            atomicAdd(&qAcc[tx*4+j], q4[j]);
        }
        __syncthreads();
        if (tid < 64) { atomicAdd(statS + tid, sAcc[tid]); atomicAdd(statQ + tid, qAcc[tid]); }
        return;
    } else {
        // bn0 + relu
#pragma unroll
        for (int j = 0; j < 4; ++j) {
            float a = bnab0[tx*4+j], sh = bnab0[64 + tx*4+j];
#pragma unroll
            for (int i = 0; i < 4; ++i) acc[i][j] = fmaxf(fmaf(a, acc[i][j], sh), 0.f);
        }
        __syncthreads();   // everyone done reading Wb
#pragma unroll
        for (int i = 0; i < 4; ++i)
#pragma unroll
            for (int j = 0; j < 4; ++j) Gb[(ty*4+i)*64 + tx*4+j] = acc[i][j];
        for (int i = tid; i < 64*64; i += 256) Wb[i] = wt1[i];
        __syncthreads();

        // ---- layer 1 GEMM ----
        float acc2[4][4];
#pragma unroll
        for (int j = 0; j < 4; ++j) {
            float bv = cb1[tx*4+j];
#pragma unroll
            for (int i = 0; i < 4; ++i) acc2[i][j] = bv;
        }
#pragma unroll 4
        for (int c = 0; c < 64; ++c) {
            float xa[4];
#pragma unroll
            for (int i = 0; i < 4; ++i) xa[i] = Gb[(ty*4+i)*64 + c];
            float4 w4 = *(const float4*)(Wb + c*64 + tx*4);
            float wb4[4] = {w4.x, w4.y, w4.z, w4.w};
#pragma unroll
            for (int i = 0; i < 4; ++i)
#pragma unroll
                for (int j = 0; j < 4; ++j) acc2[i][j] = fmaf(xa[i], wb4[j], acc2[i][j]);
        }

        if constexpr (DEPTH == 2) {
            float s4[4] = {0,0,0,0}, q4[4] = {0,0,0,0};
#pragma unroll
            for (int i = 0; i < 4; ++i)
#pragma unroll
                for (int j = 0; j < 4; ++j) { s4[j] += acc2[i][j]; q4[j] += acc2[i][j]*acc2[i][j]; }
#pragma unroll
            for (int j = 0; j < 4; ++j) {
                atomicAdd(&sAcc[tx*4+j], s4[j]);
                atomicAdd(&qAcc[tx*4+j], q4[j]);
            }
            __syncthreads();
            if (tid < 64) { atomicAdd(statS + tid, sAcc[tid]); atomicAdd(statQ + tid, qAcc[tid]); }
            return;
        } else {
            // bn1 + relu
#pragma unroll
            for (int j = 0; j < 4; ++j) {
                float a = bnab1[tx*4+j], sh = bnab1[64 + tx*4+j];
#pragma unroll
                for (int i = 0; i < 4; ++i) acc2[i][j] = fmaxf(fmaf(a, acc2[i][j], sh), 0.f);
            }
            __syncthreads();   // everyone done reading Gb & Wb
#pragma unroll
            for (int i = 0; i < 4; ++i)
#pragma unroll
                for (int j = 0; j < 4; ++j) Gb[(ty*4+i)*64 + tx*4+j] = acc2[i][j];
            for (int i = tid; i < 64*64; i += 256) Wb[i] = wt2[(i>>6)*128 + (i&63)];
            __syncthreads();

            // ---- layer 2 GEMM, 2 halves of 64 output cols ----
            for (int h = 0; h < 2; ++h) {
                float acc3[4][4];
#pragma unroll
                for (int j = 0; j < 4; ++j) {
                    float bv = cb2[h*64 + tx*4+j];
#pragma unroll
                    for (int i = 0; i < 4; ++i) acc3[i][j] = bv;
                }
#pragma unroll 4
                for (int c = 0; c < 64; ++c) {
                    float xa[4];
#pragma unroll
                    for (int i = 0; i < 4; ++i) xa[i] = Gb[(ty*4+i)*64 + c];
                    float4 w4 = *(const float4*)(Wb + c*64 + tx*4);
                    float wb4[4] = {w4.x, w4.y, w4.z, w4.w};
#pragma unroll
                    for (int i = 0; i < 4; ++i)
#pragma unroll
                        for (int j = 0; j < 4; ++j) acc3[i][j] = fmaf(xa[i], wb4[j], acc3[i][j]);
                }
                float s4[4] = {0,0,0,0}, q4[4] = {0,0,0,0};
#pragma unroll
                for (int i = 0; i < 4; ++i)
#pragma unroll
                    for (int j = 0; j < 4; ++j) { s4[j] += acc3[i][j]; q4[j] += acc3[i][j]*acc3[i][j]; }
#pragma unroll
                for (int j = 0; j < 4; ++j) {
                    atomicAdd(&sAcc[h*64 + tx*4+j], s4[j]);
                    atomicAdd(&qAcc[h*64 + tx*4+j], q4[j]);
                }
#pragma unroll
                for (int j = 0; j < 4; ++j) {
                    float mx = fmaxf(fmaxf(acc3[0][j], acc3[1][j]), fmaxf(acc3[2][j], acc3[3][j]));
                    float mn = fminf(fminf(acc3[0][j], acc3[1][j]), fminf(acc3[2][j], acc3[3][j]));
                    mxs[ty*64 + tx*4+j] = mx;
                    mns[ty*64 + tx*4+j] = mn;
                }
                __syncthreads();
                if (tid < 128) {
                    int ql = tid >> 6, c = tid & 63;
                    float mx = mxs[(ql*8)*64 + c], mn = mns[(ql*8)*64 + c];
#pragma unroll
                    for (int w = 1; w < 8; ++w) {
                        mx = fmaxf(mx, mxs[(ql*8+w)*64 + c]);
                        mn = fminf(mn, mns[(ql*8+w)*64 + c]);
                    }
                    unsigned pk = (bf16u(mx) << 16) | bf16u(mn);
                    packed[(size_t)(blockIdx.x*2 + ql)*128 + h*64 + c] = pk;
                }
                if (h == 0) {
                    __syncthreads();   // mxs reads done; Wb reads done
                    for (int i = tid; i < 64*64; i += 256) Wb[i] = wt2[(i>>6)*128 + 64 + (i&63)];
                    __syncthreads();
                }
            }
            __syncthreads();
            if (tid < 128) { atomicAdd(statS + tid, sAcc[tid]); atomicAdd(statQ + tid, qAcc[tid]); }
        }
    }
}

// ---------------- BN finalize ----------------
template<int COUT>
__global__ void bn_finalize(const float* __restrict__ stat_s, const float* __restrict__ stat_q,
                            const float* __restrict__ gamma, const float* __restrict__ beta,
                            float* __restrict__ bnab) {
    int c = threadIdx.x;
    if (c < COUT) {
        const float inv_n = 1.f / (float)RTOT;
        float mu  = stat_s[c] * inv_n;
        float var = stat_q[c] * inv_n - mu*mu;
        float inv = 1.f / sqrtf(var + EPSF);
        float a = gamma[c] * inv;
        bnab[c] = a;
        bnab[COUT + c] = beta[c] - mu * a;
    }
}

// ---------------- final: BN2+ReLU on pooled extrema ----------------
__global__ __launch_bounds__(256) void final_out(const unsigned int* __restrict__ packed,
                                                 const float* __restrict__ bnab2,
                                                 float* __restrict__ out_np) {
    int idx = blockIdx.x*256 + threadIdx.x;
    int c = idx & 127;
    float a = bnab2[c], sh = bnab2[128 + c];
    unsigned p = packed[idx];
    float mx = __uint_as_float(p & 0xFFFF0000u);
    float mn = __uint_as_float(p << 16);
    float x = (a >= 0.f) ? mx : mn;
    out_np[idx] = fmaxf(fmaf(a, x, sh), 0.f);
}

extern "C" void kernel_launch(void* const* d_in, const int* in_sizes, int n_in,
                              void* d_out, int out_size, void* d_ws, size_t ws_size,
                              hipStream_t stream) {
    const float* xyz    = (const float*)d_in[0];
    const float* points = (const float*)d_in[1];
    const float* W0 = (const float*)d_in[2];
    const float* b0 = (const float*)d_in[3];
    const float* g0 = (const float*)d_in[4];
    const float* be0= (const float*)d_in[5];
    const float* W1 = (const float*)d_in[6];
    const float* b1 = (const float*)d_in[7];
    const float* g1 = (const float*)d_in[8];
    const float* be1= (const float*)d_in[9];
    const float* W2 = (const float*)d_in[10];
    const float* b2 = (const float*)d_in[11];
    const float* g2 = (const float*)d_in[12];
    const float* be2= (const float*)d_in[13];

    float* ws  = (float*)d_ws;
    float* out = (float*)d_out;
    float* out_newxyz = out;                        // 49152
    float* out_np     = out + 49152;                // 2097152
    float* out_fpsidx = out + 49152 + 2097152;      // 16384

    float* wt0 = ws + WT0_OFF; float* wt1 = ws + WT1_OFF; float* wt2 = ws + WT2_OFF;
    float* s0 = ws + ST_OFF;        float* q0 = s0 + 64;
    float* s1 = q0 + 64;            float* q1 = s1 + 64;
    float* s2 = q1 + 64;            float* q2 = s2 + 128;
    float* bnab0 = ws + BN_OFF;     float* bnab1 = bnab0 + 128;  float* bnab2 = bnab1 + 128;
    float* nxw   = ws + NXW_OFF;
    int*   kidx  = (int*)(ws + KIDX_OFF);
    unsigned int* packed = (unsigned int*)(ws + PK_OFF);

    prep_kernel<<<1, 256, 0, stream>>>(W0, W1, W2, ws);
    fps_kernel<<<B_, 256, 0, stream>>>(xyz, out_newxyz, out_fpsidx, nxw);
    knn_kernel<<<(B_*M_)/4, 256, 0, stream>>>(xyz, nxw, kidx);

    mlp_pass<1><<<RTOT/64, 256, 0, stream>>>(xyz, points, nxw, kidx, wt0, wt1, wt2,
        b0, b1, b2, nullptr, nullptr, s0, q0, nullptr);
    bn_finalize<64><<<1, 64, 0, stream>>>(s0, q0, g0, be0, bnab0);

    mlp_pass<2><<<RTOT/64, 256, 0, stream>>>(xyz, points, nxw, kidx, wt0, wt1, wt2,
        b0, b1, b2, bnab0, nullptr, s1, q1, nullptr);
    bn_finalize<64><<<1, 64, 0, stream>>>(s1, q1, g1, be1, bnab1);

    mlp_pass<3><<<RTOT/64, 256, 0, stream>>>(xyz, points, nxw, kidx, wt0, wt1, wt2,
        b0, b1, b2, bnab0, bnab1, s2, q2, packed);
    bn_finalize<128><<<1, 128, 0, stream>>>(s2, q2, g2, be2, bnab2);

    final_out<<<(B_*M_*128)/256, 256, 0, stream>>>(packed, bnab2, out_np);
}

// Round 4
// 2383.954 us; speedup vs baseline: 1.3333x; 1.0247x over previous
//
#include <hip/hip_runtime.h>
#include <math.h>

#define B_ 16
#define N_ 4096
#define D_ 64
#define M_ 1024
#define K_ 32
#define RTOT (B_*M_*K_)          // 524288 rows
#define EPSF 1e-5f

// ---------------- ws layout (float units) — total 2688256 floats = 10.75 MB
#define WT0_OFF   0              // [68*64]  = 4352
#define WT1_OFF   4352           // [64*64]  = 4096
#define WT2_OFF   8448           // [64*128] = 8192
#define ST_OFF    16640          // s0,q0,s1,q1 [64 each]; s2,q2 [128 each] = 512
#define BN_OFF    17152          // ab0[128] ab1[128] ab2[256] = 512
#define NXW_OFF   17664          // new_xyz f32 [16384*3]
#define KIDX_OFF  66816          // knn idx int [524288]
#define PK_OFF    591104         // packed bf16 (max,min) [16384*128] uint32

__device__ inline unsigned bf16u(float x) {
    unsigned u = __float_as_uint(x);
    return (u + 0x7FFFu + ((u >> 16) & 1u)) >> 16;   // RN-even
}

// ---------------- prep: zero stats, transpose weights ----------------
__global__ void prep_kernel(const float* __restrict__ W0, const float* __restrict__ W1,
                            const float* __restrict__ W2, float* __restrict__ ws) {
    int tid = threadIdx.x;
    float* wt0 = ws + WT0_OFF; float* wt1 = ws + WT1_OFF; float* wt2 = ws + WT2_OFF;
    float* st  = ws + ST_OFF;
    for (int i = tid; i < 512; i += 256) st[i] = 0.f;
    for (int i = tid; i < 68*64; i += 256) { int c = i >> 6, o = i & 63; wt0[i] = (c < 67) ? W0[o*67 + c] : 0.f; }
    for (int i = tid; i < 64*64; i += 256) { int c = i >> 6, o = i & 63; wt1[i] = W1[o*64 + c]; }
    for (int i = tid; i < 64*128; i += 256){ int c = i >> 7, o = i & 127; wt2[i] = W2[o*64 + c]; }
}

// ---------------- FPS v3: 256 thr, value-only DPP+readlane reduce ----------
// Per step critical path: centroid ds_read_b128 -> 16-pt update (4 parallel
// argmax sub-chains) -> 4x row_ror DPP value-max -> v_readlane rows 0/16/32/48
// + scalar max (u32 compare == f32 compare, dist>=0) -> ballot lowest-lane
// winner -> readlane gidx -> lane0 writes u64 key -> barrier -> 2x b128 read
// -> 3 u64 max -> cur. No cross-lane u64 shuffles, no LDS in wave reduce.
__global__ __launch_bounds__(256) void fps_kernel(const float* __restrict__ xyz,
                                                  float* __restrict__ out_newxyz,
                                                  float* __restrict__ out_fpsidx,
                                                  float* __restrict__ ws_newxyz) {
#pragma clang fp contract(off)
    __shared__ float4 pts[N_];
    __shared__ int selidx[M_];
    __shared__ unsigned long long red[2][4];
    const int b = blockIdx.x;
    const int tid = threadIdx.x;
    const int lane = tid & 63, wave = tid >> 6;
    const float* xb = xyz + (size_t)b * N_ * 3;
    for (int i = tid; i < N_; i += 256)
        pts[i] = make_float4(xb[i*3+0], xb[i*3+1], xb[i*3+2], 0.f);
    __syncthreads();
    float px[16], py[16], pz[16], dist[16];
#pragma unroll
    for (int j = 0; j < 16; ++j) {
        float4 p = pts[(tid << 4) + j];
        px[j] = p.x; py[j] = p.y; pz[j] = p.z;
        dist[j] = 3.4e38f;
    }
    int cur = N_/2;
    for (int t = 0; t < M_; ++t) {
        if (tid == (t & 255)) selidx[t] = cur;
        if (t == M_-1) break;
        float4 c4 = pts[cur];
        float cx = c4.x, cy = c4.y, cz = c4.z;
        float bm0 = -1.f, bm1 = -1.f, bm2 = -1.f, bm3 = -1.f;
        int bj0 = 0, bj1 = 4, bj2 = 8, bj3 = 12;
#pragma unroll
        for (int j = 0; j < 4; ++j) {
            {   // chain 0: j
                float dx = px[j]-cx, dy = py[j]-cy, dz = pz[j]-cz;
                float a = dx*dx, b2 = dy*dy, c2 = dz*dz;
                float d = (a + b2) + c2;
                float nd = fminf(dist[j], d); dist[j] = nd;
                bool bt = nd > bm0; bm0 = bt ? nd : bm0; bj0 = bt ? j : bj0;
            }
            {   // chain 1: j+4
                int k = j + 4;
                float dx = px[k]-cx, dy = py[k]-cy, dz = pz[k]-cz;
                float a = dx*dx, b2 = dy*dy, c2 = dz*dz;
                float d = (a + b2) + c2;
                float nd = fminf(dist[k], d); dist[k] = nd;
                bool bt = nd > bm1; bm1 = bt ? nd : bm1; bj1 = bt ? k : bj1;
            }
            {   // chain 2: j+8
                int k = j + 8;
                float dx = px[k]-cx, dy = py[k]-cy, dz = pz[k]-cz;
                float a = dx*dx, b2 = dy*dy, c2 = dz*dz;
                float d = (a + b2) + c2;
                float nd = fminf(dist[k], d); dist[k] = nd;
                bool bt = nd > bm2; bm2 = bt ? nd : bm2; bj2 = bt ? k : bj2;
            }
            {   // chain 3: j+12
                int k = j + 12;
                float dx = px[k]-cx, dy = py[k]-cy, dz = pz[k]-cz;
                float a = dx*dx, b2 = dy*dy, c2 = dz*dz;
                float d = (a + b2) + c2;
                float nd = fminf(dist[k], d); dist[k] = nd;
                bool bt = nd > bm3; bm3 = bt ? nd : bm3; bj3 = bt ? k : bj3;
            }
        }
        // combine chains: strict > with ascending groups keeps lowest j on ties
        float bv = bm0; int bj = bj0;
        if (bm1 > bv) { bv = bm1; bj = bj1; }
        if (bm2 > bv) { bv = bm2; bj = bj2; }
        if (bm3 > bv) { bv = bm3; bj = bj3; }
        unsigned mybits = __float_as_uint(bv);      // dist>=0: u32 order == f32 order
        // in-row (16-lane) max via DPP row_ror
        unsigned vr = mybits;
        { unsigned o = (unsigned)__builtin_amdgcn_update_dpp((int)vr,(int)vr,0x121,0xF,0xF,false); if (o > vr) vr = o; }
        { unsigned o = (unsigned)__builtin_amdgcn_update_dpp((int)vr,(int)vr,0x122,0xF,0xF,false); if (o > vr) vr = o; }
        { unsigned o = (unsigned)__builtin_amdgcn_update_dpp((int)vr,(int)vr,0x124,0xF,0xF,false); if (o > vr) vr = o; }
        { unsigned o = (unsigned)__builtin_amdgcn_update_dpp((int)vr,(int)vr,0x128,0xF,0xF,false); if (o > vr) vr = o; }
        // gather 4 row maxima -> scalar max (all SALU/readlane, no LDS pipe)
        unsigned r0 = (unsigned)__builtin_amdgcn_readlane((int)vr, 0);
        unsigned r1 = (unsigned)__builtin_amdgcn_readlane((int)vr, 16);
        unsigned r2 = (unsigned)__builtin_amdgcn_readlane((int)vr, 32);
        unsigned r3 = (unsigned)__builtin_amdgcn_readlane((int)vr, 48);
        unsigned m01 = (r0 > r1) ? r0 : r1;
        unsigned m23 = (r2 > r3) ? r2 : r3;
        unsigned vmax = (m01 > m23) ? m01 : m23;
        // lowest lane holding vmax = np.argmax tie-break (ownership ascending)
        unsigned long long mask = __ballot(mybits == vmax);
        int wl = (int)__builtin_ctzll(mask);
        int gidx = (tid << 4) + bj;
        int sel = __builtin_amdgcn_readlane(gidx, wl);
        unsigned long long key = ((unsigned long long)vmax << 32) | (unsigned)(~sel);
        int buf = t & 1;
        if (lane == 0) red[buf][wave] = key;
        __syncthreads();
        unsigned long long k0 = red[buf][0], k1 = red[buf][1];
        unsigned long long k2 = red[buf][2], k3 = red[buf][3];
        unsigned long long km01 = (k0 > k1) ? k0 : k1;
        unsigned long long km23 = (k2 > k3) ? k2 : k3;
        unsigned long long km   = (km01 > km23) ? km01 : km23;
        cur = (int)((~(unsigned)km) & (N_-1));
    }
    __syncthreads();
    for (int i = tid; i < M_; i += 256) {
        int c = selidx[i];
        out_fpsidx[b*M_ + i] = (float)c;
        float4 p = pts[c];
        size_t o3 = (size_t)(b*M_ + i)*3;
        out_newxyz[o3+0] = p.x; out_newxyz[o3+1] = p.y; out_newxyz[o3+2] = p.z;
        ws_newxyz[o3+0] = p.x;  ws_newxyz[o3+1] = p.y;  ws_newxyz[o3+2] = p.z;
    }
}

// ---------------- kNN: one wave per query ----------------
__global__ __launch_bounds__(256) void knn_kernel(const float* __restrict__ xyz,
                                                  const float* __restrict__ ws_newxyz,
                                                  int* __restrict__ knn_idx) {
#pragma clang fp contract(off)
    const int lane = threadIdx.x & 63;
    const int q = blockIdx.x * 4 + (threadIdx.x >> 6);
    const int b = q >> 10;
    const float* xb = xyz + (size_t)b * N_ * 3;
    float qx = ws_newxyz[q*3+0], qy = ws_newxyz[q*3+1], qz = ws_newxyz[q*3+2];
    float qq = qx*qx + qy*qy; qq = qq + qz*qz;
    float val[64];
    float lmV = 3.4e38f; int lmK = 0;
#pragma unroll
    for (int k = 0; k < 64; ++k) {
        int n = (k<<6) + lane;
        float x = xb[n*3+0], y = xb[n*3+1], z = xb[n*3+2];
        float pp = x*x + y*y; pp = pp + z*z;
        float dot = qx*x + qy*y; dot = dot + qz*z;
        float d = (qq + pp) - 2.0f*dot;
        val[k] = d;
        if (d < lmV) { lmV = d; lmK = k; }
    }
    unsigned int myOut = 0;
    for (int r = 0; r < 32; ++r) {
        unsigned int u = __float_as_uint(lmV);
        u = (u & 0x80000000u) ? ~u : (u | 0x80000000u);   // orderable key
        unsigned long long pk = ((unsigned long long)u << 32) | (unsigned)(lane + (lmK<<6));
#pragma unroll
        for (int off = 32; off > 0; off >>= 1) {
            unsigned long long o = __shfl_xor(pk, off);
            pk = (o < pk) ? o : pk;
        }
        unsigned g = (unsigned)pk;
        if (lane == r) myOut = g;
        if (lane == (int)(g & 63u)) {
            int kk = (int)(g >> 6);
#pragma unroll
            for (int k = 0; k < 64; ++k) if (k == kk) val[k] = 3.4e38f;
            lmV = 3.4e38f; lmK = 0;
#pragma unroll
            for (int k = 0; k < 64; ++k) if (val[k] < lmV) { lmV = val[k]; lmK = k; }
        }
    }
    if (lane < 32) knn_idx[q*32 + lane] = (int)myOut;
}

// ---------------- recompute MLP pass, depth = how many layers computed ----
// 64-row tile per block, 256 threads, 4x4 outputs per thread.
// DEPTH==1: stats for layer0.  DEPTH==2: L0+bn0+relu, stats for layer1.
// DEPTH==3: L0,L1 recomputed, L2 stats + per-group bf16-packed max/min.
template<int DEPTH>
__global__ __launch_bounds__(256) void mlp_pass(
    const float* __restrict__ xyz, const float* __restrict__ points,
    const float* __restrict__ nxw, const int* __restrict__ kidx,
    const float* __restrict__ wt0, const float* __restrict__ wt1,
    const float* __restrict__ wt2,
    const float* __restrict__ cb0, const float* __restrict__ cb1,
    const float* __restrict__ cb2,
    const float* __restrict__ bnab0, const float* __restrict__ bnab1,
    float* __restrict__ statS, float* __restrict__ statQ,
    unsigned int* __restrict__ packed)
{
    __shared__ float Xs[64*68];
    __shared__ float Wb[68*64];
    __shared__ float Gb[(DEPTH>=2) ? 64*64 : 1];
    __shared__ float sAcc[128], qAcc[128];
    __shared__ float mxs[(DEPTH==3) ? 16*64 : 1];
    __shared__ float mns[(DEPTH==3) ? 16*64 : 1];
    const int tid = threadIdx.x;
    const int r0 = blockIdx.x * 64;
    const int tx = tid & 15, ty = tid >> 4;

    // gather X0 tile [64 rows x 68 cols]
    for (int i = tid; i < 64*68; i += 256) {
        int r = i / 68, c = i - r*68;
        int gr = r0 + r;
        int q = gr >> 5;
        int n = kidx[gr];
        int bb = q >> 10;
        float v;
        if (c < 3)       v = xyz[((size_t)(bb*N_ + n))*3 + c] - nxw[q*3 + c];
        else if (c < 67) v = points[((size_t)(bb*N_ + n))*64 + (c-3)];
        else             v = 0.f;
        Xs[i] = v;
    }
    for (int i = tid; i < 68*64; i += 256) Wb[i] = wt0[i];
    if (tid < 128) { sAcc[tid] = 0.f; qAcc[tid] = 0.f; }
    __syncthreads();

    // ---- layer 0 GEMM ----
    float acc[4][4];
#pragma unroll
    for (int j = 0; j < 4; ++j) {
        float bv = cb0[tx*4+j];
#pragma unroll
        for (int i = 0; i < 4; ++i) acc[i][j] = bv;
    }
#pragma unroll 4
    for (int c = 0; c < 68; ++c) {
        float xa[4];
#pragma unroll
        for (int i = 0; i < 4; ++i) xa[i] = Xs[(ty*4+i)*68 + c];
        float4 w4 = *(const float4*)(Wb + c*64 + tx*4);
        float wb4[4] = {w4.x, w4.y, w4.z, w4.w};
#pragma unroll
        for (int i = 0; i < 4; ++i)
#pragma unroll
            for (int j = 0; j < 4; ++j) acc[i][j] = fmaf(xa[i], wb4[j], acc[i][j]);
    }

    if constexpr (DEPTH == 1) {
        float s4[4] = {0,0,0,0}, q4[4] = {0,0,0,0};
#pragma unroll
        for (int i = 0; i < 4; ++i)
#pragma unroll
            for (int j = 0; j < 4; ++j) { s4[j] += acc[i][j]; q4[j] += acc[i][j]*acc[i][j]; }
#pragma unroll
        for (int j = 0; j < 4; ++j) {
            atomicAdd(&sAcc[tx*4+j], s4[j]);
            atomicAdd(&qAcc[tx*4+j], q4[j]);
        }
        __syncthreads();
        if (tid < 64) { atomicAdd(statS + tid, sAcc[tid]); atomicAdd(statQ + tid, qAcc[tid]); }
        return;
    } else {
        // bn0 + relu
#pragma unroll
        for (int j = 0; j < 4; ++j) {
            float a = bnab0[tx*4+j], sh = bnab0[64 + tx*4+j];
#pragma unroll
            for (int i = 0; i < 4; ++i) acc[i][j] = fmaxf(fmaf(a, acc[i][j], sh), 0.f);
        }
        __syncthreads();   // everyone done reading Wb
#pragma unroll
        for (int i = 0; i < 4; ++i)
#pragma unroll
            for (int j = 0; j < 4; ++j) Gb[(ty*4+i)*64 + tx*4+j] = acc[i][j];
        for (int i = tid; i < 64*64; i += 256) Wb[i] = wt1[i];
        __syncthreads();

        // ---- layer 1 GEMM ----
        float acc2[4][4];
#pragma unroll
        for (int j = 0; j < 4; ++j) {
            float bv = cb1[tx*4+j];
#pragma unroll
            for (int i = 0; i < 4; ++i) acc2[i][j] = bv;
        }
#pragma unroll 4
        for (int c = 0; c < 64; ++c) {
            float xa[4];
#pragma unroll
            for (int i = 0; i < 4; ++i) xa[i] = Gb[(ty*4+i)*64 + c];
            float4 w4 = *(const float4*)(Wb + c*64 + tx*4);
            float wb4[4] = {w4.x, w4.y, w4.z, w4.w};
#pragma unroll
            for (int i = 0; i < 4; ++i)
#pragma unroll
                for (int j = 0; j < 4; ++j) acc2[i][j] = fmaf(xa[i], wb4[j], acc2[i][j]);
        }

        if constexpr (DEPTH == 2) {
            float s4[4] = {0,0,0,0}, q4[4] = {0,0,0,0};
#pragma unroll
            for (int i = 0; i < 4; ++i)
#pragma unroll
                for (int j = 0; j < 4; ++j) { s4[j] += acc2[i][j]; q4[j] += acc2[i][j]*acc2[i][j]; }
#pragma unroll
            for (int j = 0; j < 4; ++j) {
                atomicAdd(&sAcc[tx*4+j], s4[j]);
                atomicAdd(&qAcc[tx*4+j], q4[j]);
            }
            __syncthreads();
            if (tid < 64) { atomicAdd(statS + tid, sAcc[tid]); atomicAdd(statQ + tid, qAcc[tid]); }
            return;
        } else {
            // bn1 + relu
#pragma unroll
            for (int j = 0; j < 4; ++j) {
                float a = bnab1[tx*4+j], sh = bnab1[64 + tx*4+j];
#pragma unroll
                for (int i = 0; i < 4; ++i) acc2[i][j] = fmaxf(fmaf(a, acc2[i][j], sh), 0.f);
            }
            __syncthreads();   // everyone done reading Gb & Wb
#pragma unroll
            for (int i = 0; i < 4; ++i)
#pragma unroll
                for (int j = 0; j < 4; ++j) Gb[(ty*4+i)*64 + tx*4+j] = acc2[i][j];
            for (int i = tid; i < 64*64; i += 256) Wb[i] = wt2[(i>>6)*128 + (i&63)];
            __syncthreads();

            // ---- layer 2 GEMM, 2 halves of 64 output cols ----
            for (int h = 0; h < 2; ++h) {
                float acc3[4][4];
#pragma unroll
                for (int j = 0; j < 4; ++j) {
                    float bv = cb2[h*64 + tx*4+j];
#pragma unroll
                    for (int i = 0; i < 4; ++i) acc3[i][j] = bv;
                }
#pragma unroll 4
                for (int c = 0; c < 64; ++c) {
                    float xa[4];
#pragma unroll
                    for (int i = 0; i < 4; ++i) xa[i] = Gb[(ty*4+i)*64 + c];
                    float4 w4 = *(const float4*)(Wb + c*64 + tx*4);
                    float wb4[4] = {w4.x, w4.y, w4.z, w4.w};
#pragma unroll
                    for (int i = 0; i < 4; ++i)
#pragma unroll
                        for (int j = 0; j < 4; ++j) acc3[i][j] = fmaf(xa[i], wb4[j], acc3[i][j]);
                }
                float s4[4] = {0,0,0,0}, q4[4] = {0,0,0,0};
#pragma unroll
                for (int i = 0; i < 4; ++i)
#pragma unroll
                    for (int j = 0; j < 4; ++j) { s4[j] += acc3[i][j]; q4[j] += acc3[i][j]*acc3[i][j]; }
#pragma unroll
                for (int j = 0; j < 4; ++j) {
                    atomicAdd(&sAcc[h*64 + tx*4+j], s4[j]);
                    atomicAdd(&qAcc[h*64 + tx*4+j], q4[j]);
                }
#pragma unroll
                for (int j = 0; j < 4; ++j) {
                    float mx = fmaxf(fmaxf(acc3[0][j], acc3[1][j]), fmaxf(acc3[2][j], acc3[3][j]));
                    float mn = fminf(fminf(acc3[0][j], acc3[1][j]), fminf(acc3[2][j], acc3[3][j]));
                    mxs[ty*64 + tx*4+j] = mx;
                    mns[ty*64 + tx*4+j] = mn;
                }
                __syncthreads();
                if (tid < 128) {
                    int ql = tid >> 6, c = tid & 63;
                    float mx = mxs[(ql*8)*64 + c], mn = mns[(ql*8)*64 + c];
#pragma unroll
                    for (int w = 1; w < 8; ++w) {
                        mx = fmaxf(mx, mxs[(ql*8+w)*64 + c]);
                        mn = fminf(mn, mns[(ql*8+w)*64 + c]);
                    }
                    unsigned pk = (bf16u(mx) << 16) | bf16u(mn);
                    packed[(size_t)(blockIdx.x*2 + ql)*128 + h*64 + c] = pk;
                }
                if (h == 0) {
                    __syncthreads();   // mxs reads done; Wb reads done
                    for (int i = tid; i < 64*64; i += 256) Wb[i] = wt2[(i>>6)*128 + 64 + (i&63)];
                    __syncthreads();
                }
            }
            __syncthreads();
            if (tid < 128) { atomicAdd(statS + tid, sAcc[tid]); atomicAdd(statQ + tid, qAcc[tid]); }
        }
    }
}

// ---------------- BN finalize ----------------
template<int COUT>
__global__ void bn_finalize(const float* __restrict__ stat_s, const float* __restrict__ stat_q,
                            const float* __restrict__ gamma, const float* __restrict__ beta,
                            float* __restrict__ bnab) {
    int c = threadIdx.x;
    if (c < COUT) {
        const float inv_n = 1.f / (float)RTOT;
        float mu  = stat_s[c] * inv_n;
        float var = stat_q[c] * inv_n - mu*mu;
        float inv = 1.f / sqrtf(var + EPSF);
        float a = gamma[c] * inv;
        bnab[c] = a;
        bnab[COUT + c] = beta[c] - mu * a;
    }
}

// ---------------- final: BN2+ReLU on pooled extrema ----------------
__global__ __launch_bounds__(256) void final_out(const unsigned int* __restrict__ packed,
                                                 const float* __restrict__ bnab2,
                                                 float* __restrict__ out_np) {
    int idx = blockIdx.x*256 + threadIdx.x;
    int c = idx & 127;
    float a = bnab2[c], sh = bnab2[128 + c];
    unsigned p = packed[idx];
    float mx = __uint_as_float(p & 0xFFFF0000u);
    float mn = __uint_as_float(p << 16);
    float x = (a >= 0.f) ? mx : mn;
    out_np[idx] = fmaxf(fmaf(a, x, sh), 0.f);
}

extern "C" void kernel_launch(void* const* d_in, const int* in_sizes, int n_in,
                              void* d_out, int out_size, void* d_ws, size_t ws_size,
                              hipStream_t stream) {
    const float* xyz    = (const float*)d_in[0];
    const float* points = (const float*)d_in[1];
    const float* W0 = (const float*)d_in[2];
    const float* b0 = (const float*)d_in[3];
    const float* g0 = (const float*)d_in[4];
    const float* be0= (const float*)d_in[5];
    const float* W1 = (const float*)d_in[6];
    const float* b1 = (const float*)d_in[7];
    const float* g1 = (const float*)d_in[8];
    const float* be1= (const float*)d_in[9];
    const float* W2 = (const float*)d_in[10];
    const float* b2 = (const float*)d_in[11];
    const float* g2 = (const float*)d_in[12];
    const float* be2= (const float*)d_in[13];

    float* ws  = (float*)d_ws;
    float* out = (float*)d_out;
    float* out_newxyz = out;                        // 49152
    float* out_np     = out + 49152;                // 2097152
    float* out_fpsidx = out + 49152 + 2097152;      // 16384

    float* wt0 = ws + WT0_OFF; float* wt1 = ws + WT1_OFF; float* wt2 = ws + WT2_OFF;
    float* s0 = ws + ST_OFF;        float* q0 = s0 + 64;
    float* s1 = q0 + 64;            float* q1 = s1 + 64;
    float* s2 = q1 + 64;            float* q2 = s2 + 128;
    float* bnab0 = ws + BN_OFF;     float* bnab1 = bnab0 + 128;  float* bnab2 = bnab1 + 128;
    float* nxw   = ws + NXW_OFF;
    int*   kidx  = (int*)(ws + KIDX_OFF);
    unsigned int* packed = (unsigned int*)(ws + PK_OFF);

    prep_kernel<<<1, 256, 0, stream>>>(W0, W1, W2, ws);
    fps_kernel<<<B_, 256, 0, stream>>>(xyz, out_newxyz, out_fpsidx, nxw);
    knn_kernel<<<(B_*M_)/4, 256, 0, stream>>>(xyz, nxw, kidx);

    mlp_pass<1><<<RTOT/64, 256, 0, stream>>>(xyz, points, nxw, kidx, wt0, wt1, wt2,
        b0, b1, b2, nullptr, nullptr, s0, q0, nullptr);
    bn_finalize<64><<<1, 64, 0, stream>>>(s0, q0, g0, be0, bnab0);

    mlp_pass<2><<<RTOT/64, 256, 0, stream>>>(xyz, points, nxw, kidx, wt0, wt1, wt2,
        b0, b1, b2, bnab0, nullptr, s1, q1, nullptr);
    bn_finalize<64><<<1, 64, 0, stream>>>(s1, q1, g1, be1, bnab1);

    mlp_pass<3><<<RTOT/64, 256, 0, stream>>>(xyz, points, nxw, kidx, wt0, wt1, wt2,
        b0, b1, b2, bnab0, bnab1, s2, q2, packed);
    bn_finalize<128><<<1, 128, 0, stream>>>(s2, q2, g2, be2, bnab2);

    final_out<<<(B_*M_*128)/256, 256, 0, stream>>>(packed, bnab2, out_np);
}

// Round 5
// 2176.692 us; speedup vs baseline: 1.4603x; 1.0952x over previous
//
#include <hip/hip_runtime.h>
#include <math.h>

#define B_ 16
#define N_ 4096
#define D_ 64
#define M_ 1024
#define K_ 32
#define RTOT (B_*M_*K_)          // 524288 rows
#define EPSF 1e-5f

// ---------------- ws layout (float units) — total 2680832 floats = 10.7 MB
#define WT0B_OFF  0              // bf16 W0^T-ish [64 out][96 k] = 6144 shorts = 3072 f
#define WT1B_OFF  3072           // bf16 [64][64] = 2048 f
#define WT2B_OFF  5120           // bf16 [128][64] = 4096 f
#define ST_OFF    9216           // s0,q0,s1,q1 [64]; s2,q2 [128] = 512
#define BN_OFF    9728           // ab0[128] ab1[128] ab2[256] = 512
#define NXW_OFF   10240          // new_xyz f32 [16384*3]
#define KIDX_OFF  59392          // knn idx int [524288]
#define PK_OFF    583680         // packed bf16 (max,min) [16384*128] uint32

typedef __attribute__((ext_vector_type(8))) short bf16x8;
typedef __attribute__((ext_vector_type(4))) float f32x4;

__device__ inline unsigned bf16u(float x) {
    unsigned u = __float_as_uint(x);
    return (u + 0x7FFFu + ((u >> 16) & 1u)) >> 16;   // RN-even
}

// ---------------- prep: zero stats, bf16-convert weights (already [col][k]) --
__global__ void prep_kernel(const float* __restrict__ W0, const float* __restrict__ W1,
                            const float* __restrict__ W2, float* __restrict__ ws) {
    int tid = threadIdx.x;
    unsigned short* wt0b = (unsigned short*)(ws + WT0B_OFF);
    unsigned short* wt1b = (unsigned short*)(ws + WT1B_OFF);
    unsigned short* wt2b = (unsigned short*)(ws + WT2B_OFF);
    float* st = ws + ST_OFF;
    for (int i = tid; i < 512; i += 256) st[i] = 0.f;
    for (int i = tid; i < 64*96; i += 256) {
        int o = i / 96, k = i - o*96;
        wt0b[i] = (k < 67) ? (unsigned short)bf16u(W0[o*67 + k]) : (unsigned short)0;
    }
    for (int i = tid; i < 64*64; i += 256)  wt1b[i] = (unsigned short)bf16u(W1[i]);
    for (int i = tid; i < 128*64; i += 256) wt2b[i] = (unsigned short)bf16u(W2[i]);
}

// ---------------- FPS: unchanged from round 4 (passing, ~620us) -------------
__global__ __launch_bounds__(256) void fps_kernel(const float* __restrict__ xyz,
                                                  float* __restrict__ out_newxyz,
                                                  float* __restrict__ out_fpsidx,
                                                  float* __restrict__ ws_newxyz) {
#pragma clang fp contract(off)
    __shared__ float4 pts[N_];
    __shared__ int selidx[M_];
    __shared__ unsigned long long red[2][4];
    const int b = blockIdx.x;
    const int tid = threadIdx.x;
    const int lane = tid & 63, wave = tid >> 6;
    const float* xb = xyz + (size_t)b * N_ * 3;
    for (int i = tid; i < N_; i += 256)
        pts[i] = make_float4(xb[i*3+0], xb[i*3+1], xb[i*3+2], 0.f);
    __syncthreads();
    float px[16], py[16], pz[16], dist[16];
#pragma unroll
    for (int j = 0; j < 16; ++j) {
        float4 p = pts[(tid << 4) + j];
        px[j] = p.x; py[j] = p.y; pz[j] = p.z;
        dist[j] = 3.4e38f;
    }
    int cur = N_/2;
    for (int t = 0; t < M_; ++t) {
        if (tid == (t & 255)) selidx[t] = cur;
        if (t == M_-1) break;
        float4 c4 = pts[cur];
        float cx = c4.x, cy = c4.y, cz = c4.z;
        float bm0 = -1.f, bm1 = -1.f, bm2 = -1.f, bm3 = -1.f;
        int bj0 = 0, bj1 = 4, bj2 = 8, bj3 = 12;
#pragma unroll
        for (int j = 0; j < 4; ++j) {
            {
                float dx = px[j]-cx, dy = py[j]-cy, dz = pz[j]-cz;
                float a = dx*dx, b2 = dy*dy, c2 = dz*dz;
                float d = (a + b2) + c2;
                float nd = fminf(dist[j], d); dist[j] = nd;
                bool bt = nd > bm0; bm0 = bt ? nd : bm0; bj0 = bt ? j : bj0;
            }
            {
                int k = j + 4;
                float dx = px[k]-cx, dy = py[k]-cy, dz = pz[k]-cz;
                float a = dx*dx, b2 = dy*dy, c2 = dz*dz;
                float d = (a + b2) + c2;
                float nd = fminf(dist[k], d); dist[k] = nd;
                bool bt = nd > bm1; bm1 = bt ? nd : bm1; bj1 = bt ? k : bj1;
            }
            {
                int k = j + 8;
                float dx = px[k]-cx, dy = py[k]-cy, dz = pz[k]-cz;
                float a = dx*dx, b2 = dy*dy, c2 = dz*dz;
                float d = (a + b2) + c2;
                float nd = fminf(dist[k], d); dist[k] = nd;
                bool bt = nd > bm2; bm2 = bt ? nd : bm2; bj2 = bt ? k : bj2;
            }
            {
                int k = j + 12;
                float dx = px[k]-cx, dy = py[k]-cy, dz = pz[k]-cz;
                float a = dx*dx, b2 = dy*dy, c2 = dz*dz;
                float d = (a + b2) + c2;
                float nd = fminf(dist[k], d); dist[k] = nd;
                bool bt = nd > bm3; bm3 = bt ? nd : bm3; bj3 = bt ? k : bj3;
            }
        }
        float bv = bm0; int bj = bj0;
        if (bm1 > bv) { bv = bm1; bj = bj1; }
        if (bm2 > bv) { bv = bm2; bj = bj2; }
        if (bm3 > bv) { bv = bm3; bj = bj3; }
        unsigned mybits = __float_as_uint(bv);
        unsigned vr = mybits;
        { unsigned o = (unsigned)__builtin_amdgcn_update_dpp((int)vr,(int)vr,0x121,0xF,0xF,false); if (o > vr) vr = o; }
        { unsigned o = (unsigned)__builtin_amdgcn_update_dpp((int)vr,(int)vr,0x122,0xF,0xF,false); if (o > vr) vr = o; }
        { unsigned o = (unsigned)__builtin_amdgcn_update_dpp((int)vr,(int)vr,0x124,0xF,0xF,false); if (o > vr) vr = o; }
        { unsigned o = (unsigned)__builtin_amdgcn_update_dpp((int)vr,(int)vr,0x128,0xF,0xF,false); if (o > vr) vr = o; }
        unsigned r0 = (unsigned)__builtin_amdgcn_readlane((int)vr, 0);
        unsigned r1 = (unsigned)__builtin_amdgcn_readlane((int)vr, 16);
        unsigned r2 = (unsigned)__builtin_amdgcn_readlane((int)vr, 32);
        unsigned r3 = (unsigned)__builtin_amdgcn_readlane((int)vr, 48);
        unsigned m01 = (r0 > r1) ? r0 : r1;
        unsigned m23 = (r2 > r3) ? r2 : r3;
        unsigned vmax = (m01 > m23) ? m01 : m23;
        unsigned long long mask = __ballot(mybits == vmax);
        int wl = (int)__builtin_ctzll(mask);
        int gidx = (tid << 4) + bj;
        int sel = __builtin_amdgcn_readlane(gidx, wl);
        unsigned long long key = ((unsigned long long)vmax << 32) | (unsigned)(~sel);
        int buf = t & 1;
        if (lane == 0) red[buf][wave] = key;
        __syncthreads();
        unsigned long long k0 = red[buf][0], k1 = red[buf][1];
        unsigned long long k2 = red[buf][2], k3 = red[buf][3];
        unsigned long long km01 = (k0 > k1) ? k0 : k1;
        unsigned long long km23 = (k2 > k3) ? k2 : k3;
        unsigned long long km   = (km01 > km23) ? km01 : km23;
        cur = (int)((~(unsigned)km) & (N_-1));
    }
    __syncthreads();
    for (int i = tid; i < M_; i += 256) {
        int c = selidx[i];
        out_fpsidx[b*M_ + i] = (float)c;
        float4 p = pts[c];
        size_t o3 = (size_t)(b*M_ + i)*3;
        out_newxyz[o3+0] = p.x; out_newxyz[o3+1] = p.y; out_newxyz[o3+2] = p.z;
        ws_newxyz[o3+0] = p.x;  ws_newxyz[o3+1] = p.y;  ws_newxyz[o3+2] = p.z;
    }
}

// ---------------- kNN: unchanged ----------------
__global__ __launch_bounds__(256) void knn_kernel(const float* __restrict__ xyz,
                                                  const float* __restrict__ ws_newxyz,
                                                  int* __restrict__ knn_idx) {
#pragma clang fp contract(off)
    const int lane = threadIdx.x & 63;
    const int q = blockIdx.x * 4 + (threadIdx.x >> 6);
    const int b = q >> 10;
    const float* xb = xyz + (size_t)b * N_ * 3;
    float qx = ws_newxyz[q*3+0], qy = ws_newxyz[q*3+1], qz = ws_newxyz[q*3+2];
    float qq = qx*qx + qy*qy; qq = qq + qz*qz;
    float val[64];
    float lmV = 3.4e38f; int lmK = 0;
#pragma unroll
    for (int k = 0; k < 64; ++k) {
        int n = (k<<6) + lane;
        float x = xb[n*3+0], y = xb[n*3+1], z = xb[n*3+2];
        float pp = x*x + y*y; pp = pp + z*z;
        float dot = qx*x + qy*y; dot = dot + qz*z;
        float d = (qq + pp) - 2.0f*dot;
        val[k] = d;
        if (d < lmV) { lmV = d; lmK = k; }
    }
    unsigned int myOut = 0;
    for (int r = 0; r < 32; ++r) {
        unsigned int u = __float_as_uint(lmV);
        u = (u & 0x80000000u) ? ~u : (u | 0x80000000u);
        unsigned long long pk = ((unsigned long long)u << 32) | (unsigned)(lane + (lmK<<6));
#pragma unroll
        for (int off = 32; off > 0; off >>= 1) {
            unsigned long long o = __shfl_xor(pk, off);
            pk = (o < pk) ? o : pk;
        }
        unsigned g = (unsigned)pk;
        if (lane == r) myOut = g;
        if (lane == (int)(g & 63u)) {
            int kk = (int)(g >> 6);
#pragma unroll
            for (int k = 0; k < 64; ++k) if (k == kk) val[k] = 3.4e38f;
            lmV = 3.4e38f; lmK = 0;
#pragma unroll
            for (int k = 0; k < 64; ++k) if (val[k] < lmV) { lmV = val[k]; lmK = k; }
        }
    }
    if (lane < 32) knn_idx[q*32 + lane] = (int)myOut;
}

// ---------------- MFMA recompute MLP pass ----------------
// 64-row tile/block, 4 waves. Wave w owns rows [16w,16w+16): computes all its
// 16x16 C tiles (4 col-tiles for 64-out, 8 for 128-out) via 16x16x32 bf16 MFMA.
// A-frag: lane reads X[row=16w+(lane&15)][k=quad*8..+8] (contig bf16x8).
// B-frag: lane reads W^T[col][k] same pattern (weights already [out][in]).
// D: col=lane&15, row=quad*4+reg -> wave-local rows => NO inter-layer barrier.
// Strides: 104 (k=96) / 72 (k=64) to break LDS bank conflicts.
template<int DEPTH>
__global__ __launch_bounds__(256) void mlp_pass(
    const float* __restrict__ xyz, const float* __restrict__ points,
    const float* __restrict__ nxw, const int* __restrict__ kidx,
    const unsigned short* __restrict__ wt0b, const unsigned short* __restrict__ wt1b,
    const unsigned short* __restrict__ wt2b,
    const float* __restrict__ cb0, const float* __restrict__ cb1,
    const float* __restrict__ cb2,
    const float* __restrict__ bnab0, const float* __restrict__ bnab1,
    float* __restrict__ statS, float* __restrict__ statQ,
    unsigned int* __restrict__ packed)
{
    __shared__ __align__(16) unsigned short XsB[64*104];
    __shared__ __align__(16) unsigned short W0B[64*104];
    __shared__ __align__(16) unsigned short W1B[(DEPTH>=2) ? 64*72 : 8];
    __shared__ __align__(16) unsigned short W2B[(DEPTH==3) ? 128*72 : 8];
    __shared__ __align__(16) unsigned short Gb [(DEPTH>=2) ? 64*72 : 8];
    __shared__ float sAcc[128], qAcc[128];
    __shared__ float mxs[(DEPTH==3) ? 4*128 : 1];
    __shared__ float mns[(DEPTH==3) ? 4*128 : 1];

    const int tid = threadIdx.x;
    const int r0 = blockIdx.x * 64;
    const int lane = tid & 63, wv = tid >> 6;
    const int mrow = lane & 15, quad = lane >> 4;

    // ---- stage weights ----
    {
        const uint4* s = (const uint4*)wt0b;
        for (int i = tid; i < 768; i += 256) {          // 64 rows x 12 16B-chunks
            int r = i / 12, ch = i - r*12;
            *(uint4*)(W0B + r*104 + ch*8) = s[i];
        }
    }
    if constexpr (DEPTH >= 2) {
        const uint4* s = (const uint4*)wt1b;
        for (int i = tid; i < 512; i += 256) {          // 64 x 8
            int r = i >> 3, ch = i & 7;
            *(uint4*)(W1B + r*72 + ch*8) = s[i];
        }
    }
    if constexpr (DEPTH == 3) {
        const uint4* s = (const uint4*)wt2b;
        for (int i = tid; i < 1024; i += 256) {         // 128 x 8
            int r = i >> 3, ch = i & 7;
            *(uint4*)(W2B + r*72 + ch*8) = s[i];
        }
    }
    if (tid < 128) { sAcc[tid] = 0.f; qAcc[tid] = 0.f; }

    // ---- gather X0 tile [64][96] -> bf16 LDS stride 104 (cols 67..95 zero) --
    for (int i = tid; i < 64*96; i += 256) {
        int r = i / 96, c = i - r*96;
        int gr = r0 + r;
        int q = gr >> 5;
        int n = kidx[gr];
        int bb = q >> 10;
        float v = 0.f;
        if (c < 3)       v = xyz[((size_t)(bb*N_ + n))*3 + c] - nxw[q*3 + c];
        else if (c < 67) v = points[((size_t)(bb*N_ + n))*64 + (c-3)];
        XsB[r*104 + c] = (unsigned short)bf16u(v);
    }
    __syncthreads();

    const int arow = wv*16 + mrow;

    // ---- layer 0: 64 out, K=96 ----
    f32x4 acc0[4];
#pragma unroll
    for (int ct = 0; ct < 4; ++ct) {
        float bv = cb0[ct*16 + mrow];
        acc0[ct] = (f32x4){bv, bv, bv, bv};
    }
#pragma unroll
    for (int kk = 0; kk < 96; kk += 32) {
        bf16x8 a = *(const bf16x8*)(XsB + arow*104 + kk + quad*8);
#pragma unroll
        for (int ct = 0; ct < 4; ++ct) {
            bf16x8 b = *(const bf16x8*)(W0B + (ct*16 + mrow)*104 + kk + quad*8);
            acc0[ct] = __builtin_amdgcn_mfma_f32_16x16x32_bf16(a, b, acc0[ct], 0, 0, 0);
        }
    }

    if constexpr (DEPTH == 1) {
#pragma unroll
        for (int ct = 0; ct < 4; ++ct) {
            f32x4 v = acc0[ct];
            float s = (v.x + v.y) + (v.z + v.w);
            float q = (v.x*v.x + v.y*v.y) + (v.z*v.z + v.w*v.w);
            atomicAdd(&sAcc[ct*16 + mrow], s);
            atomicAdd(&qAcc[ct*16 + mrow], q);
        }
        __syncthreads();
        if (tid < 64) { atomicAdd(statS + tid, sAcc[tid]); atomicAdd(statQ + tid, qAcc[tid]); }
        return;
    } else {
        // bn0+relu -> Gb (wave-local rows, no barrier)
        const int rbase = wv*16 + quad*4;
#pragma unroll
        for (int ct = 0; ct < 4; ++ct) {
            int col = ct*16 + mrow;
            float a = bnab0[col], sh = bnab0[64 + col];
            f32x4 v = acc0[ct];
            Gb[(rbase+0)*72 + col] = (unsigned short)bf16u(fmaxf(fmaf(a, v.x, sh), 0.f));
            Gb[(rbase+1)*72 + col] = (unsigned short)bf16u(fmaxf(fmaf(a, v.y, sh), 0.f));
            Gb[(rbase+2)*72 + col] = (unsigned short)bf16u(fmaxf(fmaf(a, v.z, sh), 0.f));
            Gb[(rbase+3)*72 + col] = (unsigned short)bf16u(fmaxf(fmaf(a, v.w, sh), 0.f));
        }

        // ---- layer 1: 64 out, K=64 ----
        f32x4 acc1[4];
#pragma unroll
        for (int ct = 0; ct < 4; ++ct) {
            float bv = cb1[ct*16 + mrow];
            acc1[ct] = (f32x4){bv, bv, bv, bv};
        }
#pragma unroll
        for (int kk = 0; kk < 64; kk += 32) {
            bf16x8 a = *(const bf16x8*)(Gb + arow*72 + kk + quad*8);
#pragma unroll
            for (int ct = 0; ct < 4; ++ct) {
                bf16x8 b = *(const bf16x8*)(W1B + (ct*16 + mrow)*72 + kk + quad*8);
                acc1[ct] = __builtin_amdgcn_mfma_f32_16x16x32_bf16(a, b, acc1[ct], 0, 0, 0);
            }
        }

        if constexpr (DEPTH == 2) {
#pragma unroll
            for (int ct = 0; ct < 4; ++ct) {
                f32x4 v = acc1[ct];
                float s = (v.x + v.y) + (v.z + v.w);
                float q = (v.x*v.x + v.y*v.y) + (v.z*v.z + v.w*v.w);
                atomicAdd(&sAcc[ct*16 + mrow], s);
                atomicAdd(&qAcc[ct*16 + mrow], q);
            }
            __syncthreads();
            if (tid < 64) { atomicAdd(statS + tid, sAcc[tid]); atomicAdd(statQ + tid, qAcc[tid]); }
            return;
        } else {
            // bn1+relu -> Gb overwrite (same wave-local rows, in-order LDS)
#pragma unroll
            for (int ct = 0; ct < 4; ++ct) {
                int col = ct*16 + mrow;
                float a = bnab1[col], sh = bnab1[64 + col];
                f32x4 v = acc1[ct];
                Gb[(rbase+0)*72 + col] = (unsigned short)bf16u(fmaxf(fmaf(a, v.x, sh), 0.f));
                Gb[(rbase+1)*72 + col] = (unsigned short)bf16u(fmaxf(fmaf(a, v.y, sh), 0.f));
                Gb[(rbase+2)*72 + col] = (unsigned short)bf16u(fmaxf(fmaf(a, v.z, sh), 0.f));
                Gb[(rbase+3)*72 + col] = (unsigned short)bf16u(fmaxf(fmaf(a, v.w, sh), 0.f));
            }

            // ---- layer 2: 128 out, K=64 ----
            f32x4 acc2[8];
#pragma unroll
            for (int ct = 0; ct < 8; ++ct) {
                float bv = cb2[ct*16 + mrow];
                acc2[ct] = (f32x4){bv, bv, bv, bv};
            }
#pragma unroll
            for (int kk = 0; kk < 64; kk += 32) {
                bf16x8 a = *(const bf16x8*)(Gb + arow*72 + kk + quad*8);
#pragma unroll
                for (int ct = 0; ct < 8; ++ct) {
                    bf16x8 b = *(const bf16x8*)(W2B + (ct*16 + mrow)*72 + kk + quad*8);
                    acc2[ct] = __builtin_amdgcn_mfma_f32_16x16x32_bf16(a, b, acc2[ct], 0, 0, 0);
                }
            }

            // stats (no barrier needed yet)
#pragma unroll
            for (int ct = 0; ct < 8; ++ct) {
                f32x4 v = acc2[ct];
                float s = (v.x + v.y) + (v.z + v.w);
                float q = (v.x*v.x + v.y*v.y) + (v.z*v.z + v.w*v.w);
                atomicAdd(&sAcc[ct*16 + mrow], s);
                atomicAdd(&qAcc[ct*16 + mrow], q);
            }
            // extrema: per-lane over 4 rows, cross-quad shfl, lane<16 writes
#pragma unroll
            for (int ct = 0; ct < 8; ++ct) {
                f32x4 v = acc2[ct];
                float mx = fmaxf(fmaxf(v.x, v.y), fmaxf(v.z, v.w));
                float mn = fminf(fminf(v.x, v.y), fminf(v.z, v.w));
                { float o = __shfl_xor(mx, 16); mx = fmaxf(mx, o); }
                { float o = __shfl_xor(mn, 16); mn = fminf(mn, o); }
                { float o = __shfl_xor(mx, 32); mx = fmaxf(mx, o); }
                { float o = __shfl_xor(mn, 32); mn = fminf(mn, o); }
                if (quad == 0) {
                    mxs[wv*128 + ct*16 + mrow] = mx;
                    mns[wv*128 + ct*16 + mrow] = mn;
                }
            }
            __syncthreads();
            // combine wave pairs -> 2 groups x 128 cols, pack bf16
            {
                int g = tid >> 7, c = tid & 127;
                float mx = fmaxf(mxs[(2*g)*128 + c], mxs[(2*g+1)*128 + c]);
                float mn = fminf(mns[(2*g)*128 + c], mns[(2*g+1)*128 + c]);
                packed[(size_t)(blockIdx.x*2 + g)*128 + c] = (bf16u(mx) << 16) | bf16u(mn);
            }
            if (tid < 128) { atomicAdd(statS + tid, sAcc[tid]); atomicAdd(statQ + tid, qAcc[tid]); }
        }
    }
}

// ---------------- BN finalize ----------------
template<int COUT>
__global__ void bn_finalize(const float* __restrict__ stat_s, const float* __restrict__ stat_q,
                            const float* __restrict__ gamma, const float* __restrict__ beta,
                            float* __restrict__ bnab) {
    int c = threadIdx.x;
    if (c < COUT) {
        const float inv_n = 1.f / (float)RTOT;
        float mu  = stat_s[c] * inv_n;
        float var = stat_q[c] * inv_n - mu*mu;
        float inv = 1.f / sqrtf(var + EPSF);
        float a = gamma[c] * inv;
        bnab[c] = a;
        bnab[COUT + c] = beta[c] - mu * a;
    }
}

// ---------------- final: BN2+ReLU on pooled extrema ----------------
__global__ __launch_bounds__(256) void final_out(const unsigned int* __restrict__ packed,
                                                 const float* __restrict__ bnab2,
                                                 float* __restrict__ out_np) {
    int idx = blockIdx.x*256 + threadIdx.x;
    int c = idx & 127;
    float a = bnab2[c], sh = bnab2[128 + c];
    unsigned p = packed[idx];
    float mx = __uint_as_float(p & 0xFFFF0000u);
    float mn = __uint_as_float(p << 16);
    float x = (a >= 0.f) ? mx : mn;
    out_np[idx] = fmaxf(fmaf(a, x, sh), 0.f);
}

extern "C" void kernel_launch(void* const* d_in, const int* in_sizes, int n_in,
                              void* d_out, int out_size, void* d_ws, size_t ws_size,
                              hipStream_t stream) {
    const float* xyz    = (const float*)d_in[0];
    const float* points = (const float*)d_in[1];
    const float* W0 = (const float*)d_in[2];
    const float* b0 = (const float*)d_in[3];
    const float* g0 = (const float*)d_in[4];
    const float* be0= (const float*)d_in[5];
    const float* W1 = (const float*)d_in[6];
    const float* b1 = (const float*)d_in[7];
    const float* g1 = (const float*)d_in[8];
    const float* be1= (const float*)d_in[9];
    const float* W2 = (const float*)d_in[10];
    const float* b2 = (const float*)d_in[11];
    const float* g2 = (const float*)d_in[12];
    const float* be2= (const float*)d_in[13];

    float* ws  = (float*)d_ws;
    float* out = (float*)d_out;
    float* out_newxyz = out;                        // 49152
    float* out_np     = out + 49152;                // 2097152
    float* out_fpsidx = out + 49152 + 2097152;      // 16384

    unsigned short* wt0b = (unsigned short*)(ws + WT0B_OFF);
    unsigned short* wt1b = (unsigned short*)(ws + WT1B_OFF);
    unsigned short* wt2b = (unsigned short*)(ws + WT2B_OFF);
    float* s0 = ws + ST_OFF;        float* q0 = s0 + 64;
    float* s1 = q0 + 64;            float* q1 = s1 + 64;
    float* s2 = q1 + 64;            float* q2 = s2 + 128;
    float* bnab0 = ws + BN_OFF;     float* bnab1 = bnab0 + 128;  float* bnab2 = bnab1 + 128;
    float* nxw   = ws + NXW_OFF;
    int*   kidx  = (int*)(ws + KIDX_OFF);
    unsigned int* packed = (unsigned int*)(ws + PK_OFF);

    prep_kernel<<<1, 256, 0, stream>>>(W0, W1, W2, ws);
    fps_kernel<<<B_, 256, 0, stream>>>(xyz, out_newxyz, out_fpsidx, nxw);
    knn_kernel<<<(B_*M_)/4, 256, 0, stream>>>(xyz, nxw, kidx);

    mlp_pass<1><<<RTOT/64, 256, 0, stream>>>(xyz, points, nxw, kidx, wt0b, wt1b, wt2b,
        b0, b1, b2, nullptr, nullptr, s0, q0, nullptr);
    bn_finalize<64><<<1, 64, 0, stream>>>(s0, q0, g0, be0, bnab0);

    mlp_pass<2><<<RTOT/64, 256, 0, stream>>>(xyz, points, nxw, kidx, wt0b, wt1b, wt2b,
        b0, b1, b2, bnab0, nullptr, s1, q1, nullptr);
    bn_finalize<64><<<1, 64, 0, stream>>>(s1, q1, g1, be1, bnab1);

    mlp_pass<3><<<RTOT/64, 256, 0, stream>>>(xyz, points, nxw, kidx, wt0b, wt1b, wt2b,
        b0, b1, b2, bnab0, bnab1, s2, q2, packed);
    bn_finalize<128><<<1, 128, 0, stream>>>(s2, q2, g2, be2, bnab2);

    final_out<<<(B_*M_*128)/256, 256, 0, stream>>>(packed, bnab2, out_np);
}

// Round 6
// 1867.716 us; speedup vs baseline: 1.7018x; 1.1654x over previous
//
#include <hip/hip_runtime.h>
#include <math.h>

#define B_ 16
#define N_ 4096
#define D_ 64
#define M_ 1024
#define K_ 32
#define RTOT (B_*M_*K_)          // 524288 rows
#define EPSF 1e-5f

// ---------------- ws layout (float units)
// base region (10.7 MB) + optional Y0/Y1 bf16 intermediates (134 MB)
#define WT0B_OFF  0              // bf16 W0 perm [64 out][96 k] = 3072 f
#define WT1B_OFF  3072           // bf16 [64][64] = 2048 f
#define WT2B_OFF  5120           // bf16 [128][64] = 4096 f
#define ST_OFF    9216           // s0,q0,s1,q1 [64]; s2,q2 [128] = 512
#define BN_OFF    9728           // ab0[128] ab1[128] ab2[256] = 512
#define NXW_OFF   10240          // new_xyz f32 [16384*3]
#define KIDX_OFF  59392          // knn idx int [524288]
#define PK_OFF    583680         // packed bf16 (max,min) [16384*128] uint32
#define Y0B_OFF   2680832        // bf16 Y0 raw [524288*64] = 16777216 f
#define Y1B_OFF   19458048       // bf16 Y1 raw [524288*64] = 16777216 f
#define WS_NEED_BYTES (36235264ull * 4ull)   // ~145 MB for fast path

typedef __attribute__((ext_vector_type(8))) short bf16x8;
typedef __attribute__((ext_vector_type(4))) float f32x4;

__device__ inline unsigned bf16u(float x) {
    unsigned u = __float_as_uint(x);
    return (u + 0x7FFFu + ((u >> 16) & 1u)) >> 16;   // RN-even
}
__device__ inline float ubf(unsigned short h) {
    return __uint_as_float(((unsigned)h) << 16);
}

// ---------------- prep: zero stats, bf16 weights; W0 cols permuted:
// k 0..63 = feature weights (orig cols 3..66), k 64..66 = xyz (orig 0..2), 67..95 = 0
__global__ void prep_kernel(const float* __restrict__ W0, const float* __restrict__ W1,
                            const float* __restrict__ W2, float* __restrict__ ws) {
    int tid = threadIdx.x;
    unsigned short* wt0b = (unsigned short*)(ws + WT0B_OFF);
    unsigned short* wt1b = (unsigned short*)(ws + WT1B_OFF);
    unsigned short* wt2b = (unsigned short*)(ws + WT2B_OFF);
    float* st = ws + ST_OFF;
    for (int i = tid; i < 512; i += 256) st[i] = 0.f;
    for (int i = tid; i < 64*96; i += 256) {
        int o = i / 96, k = i - o*96;
        float w = 0.f;
        if (k < 64)      w = W0[o*67 + 3 + k];
        else if (k < 67) w = W0[o*67 + (k - 64)];
        wt0b[i] = (unsigned short)bf16u(w);
    }
    for (int i = tid; i < 64*64; i += 256)  wt1b[i] = (unsigned short)bf16u(W1[i]);
    for (int i = tid; i < 128*64; i += 256) wt2b[i] = (unsigned short)bf16u(W2[i]);
}

// ---------------- FPS: unchanged (verified) ----------------
__global__ __launch_bounds__(256) void fps_kernel(const float* __restrict__ xyz,
                                                  float* __restrict__ out_newxyz,
                                                  float* __restrict__ out_fpsidx,
                                                  float* __restrict__ ws_newxyz) {
#pragma clang fp contract(off)
    __shared__ float4 pts[N_];
    __shared__ int selidx[M_];
    __shared__ unsigned long long red[2][4];
    const int b = blockIdx.x;
    const int tid = threadIdx.x;
    const int lane = tid & 63, wave = tid >> 6;
    const float* xb = xyz + (size_t)b * N_ * 3;
    for (int i = tid; i < N_; i += 256)
        pts[i] = make_float4(xb[i*3+0], xb[i*3+1], xb[i*3+2], 0.f);
    __syncthreads();
    float px[16], py[16], pz[16], dist[16];
#pragma unroll
    for (int j = 0; j < 16; ++j) {
        float4 p = pts[(tid << 4) + j];
        px[j] = p.x; py[j] = p.y; pz[j] = p.z;
        dist[j] = 3.4e38f;
    }
    int cur = N_/2;
    for (int t = 0; t < M_; ++t) {
        if (tid == (t & 255)) selidx[t] = cur;
        if (t == M_-1) break;
        float4 c4 = pts[cur];
        float cx = c4.x, cy = c4.y, cz = c4.z;
        float bm0 = -1.f, bm1 = -1.f, bm2 = -1.f, bm3 = -1.f;
        int bj0 = 0, bj1 = 4, bj2 = 8, bj3 = 12;
#pragma unroll
        for (int j = 0; j < 4; ++j) {
            {
                float dx = px[j]-cx, dy = py[j]-cy, dz = pz[j]-cz;
                float a = dx*dx, b2 = dy*dy, c2 = dz*dz;
                float d = (a + b2) + c2;
                float nd = fminf(dist[j], d); dist[j] = nd;
                bool bt = nd > bm0; bm0 = bt ? nd : bm0; bj0 = bt ? j : bj0;
            }
            {
                int k = j + 4;
                float dx = px[k]-cx, dy = py[k]-cy, dz = pz[k]-cz;
                float a = dx*dx, b2 = dy*dy, c2 = dz*dz;
                float d = (a + b2) + c2;
                float nd = fminf(dist[k], d); dist[k] = nd;
                bool bt = nd > bm1; bm1 = bt ? nd : bm1; bj1 = bt ? k : bj1;
            }
            {
                int k = j + 8;
                float dx = px[k]-cx, dy = py[k]-cy, dz = pz[k]-cz;
                float a = dx*dx, b2 = dy*dy, c2 = dz*dz;
                float d = (a + b2) + c2;
                float nd = fminf(dist[k], d); dist[k] = nd;
                bool bt = nd > bm2; bm2 = bt ? nd : bm2; bj2 = bt ? k : bj2;
            }
            {
                int k = j + 12;
                float dx = px[k]-cx, dy = py[k]-cy, dz = pz[k]-cz;
                float a = dx*dx, b2 = dy*dy, c2 = dz*dz;
                float d = (a + b2) + c2;
                float nd = fminf(dist[k], d); dist[k] = nd;
                bool bt = nd > bm3; bm3 = bt ? nd : bm3; bj3 = bt ? k : bj3;
            }
        }
        float bv = bm0; int bj = bj0;
        if (bm1 > bv) { bv = bm1; bj = bj1; }
        if (bm2 > bv) { bv = bm2; bj = bj2; }
        if (bm3 > bv) { bv = bm3; bj = bj3; }
        unsigned mybits = __float_as_uint(bv);
        unsigned vr = mybits;
        { unsigned o = (unsigned)__builtin_amdgcn_update_dpp((int)vr,(int)vr,0x121,0xF,0xF,false); if (o > vr) vr = o; }
        { unsigned o = (unsigned)__builtin_amdgcn_update_dpp((int)vr,(int)vr,0x122,0xF,0xF,false); if (o > vr) vr = o; }
        { unsigned o = (unsigned)__builtin_amdgcn_update_dpp((int)vr,(int)vr,0x124,0xF,0xF,false); if (o > vr) vr = o; }
        { unsigned o = (unsigned)__builtin_amdgcn_update_dpp((int)vr,(int)vr,0x128,0xF,0xF,false); if (o > vr) vr = o; }
        unsigned r0 = (unsigned)__builtin_amdgcn_readlane((int)vr, 0);
        unsigned r1 = (unsigned)__builtin_amdgcn_readlane((int)vr, 16);
        unsigned r2 = (unsigned)__builtin_amdgcn_readlane((int)vr, 32);
        unsigned r3 = (unsigned)__builtin_amdgcn_readlane((int)vr, 48);
        unsigned m01 = (r0 > r1) ? r0 : r1;
        unsigned m23 = (r2 > r3) ? r2 : r3;
        unsigned vmax = (m01 > m23) ? m01 : m23;
        unsigned long long mask = __ballot(mybits == vmax);
        int wl = (int)__builtin_ctzll(mask);
        int gidx = (tid << 4) + bj;
        int sel = __builtin_amdgcn_readlane(gidx, wl);
        unsigned long long key = ((unsigned long long)vmax << 32) | (unsigned)(~sel);
        int buf = t & 1;
        if (lane == 0) red[buf][wave] = key;
        __syncthreads();
        unsigned long long k0 = red[buf][0], k1 = red[buf][1];
        unsigned long long k2 = red[buf][2], k3 = red[buf][3];
        unsigned long long km01 = (k0 > k1) ? k0 : k1;
        unsigned long long km23 = (k2 > k3) ? k2 : k3;
        unsigned long long km   = (km01 > km23) ? km01 : km23;
        cur = (int)((~(unsigned)km) & (N_-1));
    }
    __syncthreads();
    for (int i = tid; i < M_; i += 256) {
        int c = selidx[i];
        out_fpsidx[b*M_ + i] = (float)c;
        float4 p = pts[c];
        size_t o3 = (size_t)(b*M_ + i)*3;
        out_newxyz[o3+0] = p.x; out_newxyz[o3+1] = p.y; out_newxyz[o3+2] = p.z;
        ws_newxyz[o3+0] = p.x;  ws_newxyz[o3+1] = p.y;  ws_newxyz[o3+2] = p.z;
    }
}

// ---------------- kNN: unchanged (verified) ----------------
__global__ __launch_bounds__(256) void knn_kernel(const float* __restrict__ xyz,
                                                  const float* __restrict__ ws_newxyz,
                                                  int* __restrict__ knn_idx) {
#pragma clang fp contract(off)
    const int lane = threadIdx.x & 63;
    const int q = blockIdx.x * 4 + (threadIdx.x >> 6);
    const int b = q >> 10;
    const float* xb = xyz + (size_t)b * N_ * 3;
    float qx = ws_newxyz[q*3+0], qy = ws_newxyz[q*3+1], qz = ws_newxyz[q*3+2];
    float qq = qx*qx + qy*qy; qq = qq + qz*qz;
    float val[64];
    float lmV = 3.4e38f; int lmK = 0;
#pragma unroll
    for (int k = 0; k < 64; ++k) {
        int n = (k<<6) + lane;
        float x = xb[n*3+0], y = xb[n*3+1], z = xb[n*3+2];
        float pp = x*x + y*y; pp = pp + z*z;
        float dot = qx*x + qy*y; dot = dot + qz*z;
        float d = (qq + pp) - 2.0f*dot;
        val[k] = d;
        if (d < lmV) { lmV = d; lmK = k; }
    }
    unsigned int myOut = 0;
    for (int r = 0; r < 32; ++r) {
        unsigned int u = __float_as_uint(lmV);
        u = (u & 0x80000000u) ? ~u : (u | 0x80000000u);
        unsigned long long pk = ((unsigned long long)u << 32) | (unsigned)(lane + (lmK<<6));
#pragma unroll
        for (int off = 32; off > 0; off >>= 1) {
            unsigned long long o = __shfl_xor(pk, off);
            pk = (o < pk) ? o : pk;
        }
        unsigned g = (unsigned)pk;
        if (lane == r) myOut = g;
        if (lane == (int)(g & 63u)) {
            int kk = (int)(g >> 6);
#pragma unroll
            for (int k = 0; k < 64; ++k) if (k == kk) val[k] = 3.4e38f;
            lmV = 3.4e38f; lmK = 0;
#pragma unroll
            for (int k = 0; k < 64; ++k) if (val[k] < lmV) { lmV = val[k]; lmK = k; }
        }
    }
    if (lane < 32) knn_idx[q*32 + lane] = (int)myOut;
}

// ================== FAST PATH (stored intermediates) ==================
// pass0: gather X0 (features-first), L0 MFMA, store raw Y0 bf16, stats0.
__global__ __launch_bounds__(256) void pass0_kernel(
    const float* __restrict__ xyz, const float* __restrict__ points,
    const float* __restrict__ nxw, const int* __restrict__ kidx,
    const unsigned short* __restrict__ wt0b, const float* __restrict__ cb0,
    float* __restrict__ statS, float* __restrict__ statQ,
    unsigned short* __restrict__ y0b)
{
    __shared__ __align__(16) unsigned short XsB[64*104];
    __shared__ __align__(16) unsigned short W0B[64*104];   // reused as store stage [64*72]
    __shared__ int sidx[64];
    __shared__ float sAcc[64], qAcc[64];
    const int tid = threadIdx.x;
    const int r0 = blockIdx.x * 64;
    const int lane = tid & 63, wv = tid >> 6;
    const int mrow = lane & 15, quad = lane >> 4;

    if (tid < 64) { sidx[tid] = kidx[r0 + tid]; sAcc[tid] = 0.f; qAcc[tid] = 0.f; }
    {
        const uint4* s = (const uint4*)wt0b;
        for (int i = tid; i < 768; i += 256) {
            int r = i / 12, ch = i - r*12;
            *(uint4*)(W0B + r*104 + ch*8) = s[i];
        }
    }
    __syncthreads();

    // gather: thread = (row, q4); features cols q4*16..+16, q4==0 also rel-xyz @64..66
    {
        int row = tid >> 2, q4 = tid & 3;
        int gr = r0 + row;
        int qq = gr >> 5, bb = qq >> 10;
        int n = sidx[row];
        const float4* src = (const float4*)(points + ((size_t)(bb*N_ + n))*64 + q4*16);
        float4 f0 = src[0], f1 = src[1], f2 = src[2], f3 = src[3];
        uint4 u0, u1;
        u0.x = bf16u(f0.x) | (bf16u(f0.y) << 16);
        u0.y = bf16u(f0.z) | (bf16u(f0.w) << 16);
        u0.z = bf16u(f1.x) | (bf16u(f1.y) << 16);
        u0.w = bf16u(f1.z) | (bf16u(f1.w) << 16);
        u1.x = bf16u(f2.x) | (bf16u(f2.y) << 16);
        u1.y = bf16u(f2.z) | (bf16u(f2.w) << 16);
        u1.z = bf16u(f3.x) | (bf16u(f3.y) << 16);
        u1.w = bf16u(f3.z) | (bf16u(f3.w) << 16);
        *(uint4*)(XsB + row*104 + q4*16)     = u0;
        *(uint4*)(XsB + row*104 + q4*16 + 8) = u1;
        uint4 z; 
        if (q4 == 0) {
            float rx = xyz[((size_t)(bb*N_ + n))*3 + 0] - nxw[qq*3 + 0];
            float ry = xyz[((size_t)(bb*N_ + n))*3 + 1] - nxw[qq*3 + 1];
            float rz = xyz[((size_t)(bb*N_ + n))*3 + 2] - nxw[qq*3 + 2];
            z.x = bf16u(rx) | (bf16u(ry) << 16);
            z.y = bf16u(rz);
            z.z = 0; z.w = 0;
        } else { z.x = 0; z.y = 0; z.z = 0; z.w = 0; }
        *(uint4*)(XsB + row*104 + 64 + q4*8) = z;
    }
    __syncthreads();

    const int arow = wv*16 + mrow;
    f32x4 acc0[4];
#pragma unroll
    for (int ct = 0; ct < 4; ++ct) {
        float bv = cb0[ct*16 + mrow];
        acc0[ct] = (f32x4){bv, bv, bv, bv};
    }
#pragma unroll
    for (int kk = 0; kk < 96; kk += 32) {
        bf16x8 a = *(const bf16x8*)(XsB + arow*104 + kk + quad*8);
#pragma unroll
        for (int ct = 0; ct < 4; ++ct) {
            bf16x8 b = *(const bf16x8*)(W0B + (ct*16 + mrow)*104 + kk + quad*8);
            acc0[ct] = __builtin_amdgcn_mfma_f32_16x16x32_bf16(a, b, acc0[ct], 0, 0, 0);
        }
    }
#pragma unroll
    for (int ct = 0; ct < 4; ++ct) {
        f32x4 v = acc0[ct];
        float s = (v.x + v.y) + (v.z + v.w);
        float q = (v.x*v.x + v.y*v.y) + (v.z*v.z + v.w*v.w);
        atomicAdd(&sAcc[ct*16 + mrow], s);
        atomicAdd(&qAcc[ct*16 + mrow], q);
    }
    __syncthreads();   // W0B reads done
    unsigned short* STG = W0B;
    const int rbase = wv*16 + quad*4;
#pragma unroll
    for (int ct = 0; ct < 4; ++ct) {
        int col = ct*16 + mrow;
        f32x4 v = acc0[ct];
        STG[(rbase+0)*72 + col] = (unsigned short)bf16u(v.x);
        STG[(rbase+1)*72 + col] = (unsigned short)bf16u(v.y);
        STG[(rbase+2)*72 + col] = (unsigned short)bf16u(v.z);
        STG[(rbase+3)*72 + col] = (unsigned short)bf16u(v.w);
    }
    __syncthreads();
    for (int i = tid; i < 512; i += 256) {
        int r = i >> 3, c8 = i & 7;
        *(uint4*)(y0b + (size_t)(r0 + r)*64 + c8*8) = *(const uint4*)(STG + r*72 + c8*8);
    }
    if (tid < 64) { atomicAdd(statS + tid, sAcc[tid]); atomicAdd(statQ + tid, qAcc[tid]); }
}

// pass1: stream Y0, bn0+relu in-register, L1 MFMA, store raw Y1 bf16, stats1.
__global__ __launch_bounds__(256) void pass1_kernel(
    const unsigned short* __restrict__ y0b, const unsigned short* __restrict__ wt1b,
    const float* __restrict__ cb1, const float* __restrict__ bnab0,
    float* __restrict__ statS, float* __restrict__ statQ,
    unsigned short* __restrict__ y1b)
{
    __shared__ __align__(16) unsigned short W1B[64*72];
    __shared__ __align__(16) unsigned short STG[64*72];
    __shared__ float sAcc[64], qAcc[64];
    const int tid = threadIdx.x;
    const int r0 = blockIdx.x * 64;
    const int lane = tid & 63, wv = tid >> 6;
    const int mrow = lane & 15, quad = lane >> 4;

    {
        const uint4* s = (const uint4*)wt1b;
        for (int i = tid; i < 512; i += 256) {
            int r = i >> 3, ch = i & 7;
            *(uint4*)(W1B + r*72 + ch*8) = s[i];
        }
    }
    if (tid < 64) { sAcc[tid] = 0.f; qAcc[tid] = 0.f; }

    const int gr = r0 + wv*16 + mrow;
    bf16x8 raw0 = *(const bf16x8*)(y0b + (size_t)gr*64 + quad*8);
    bf16x8 raw1 = *(const bf16x8*)(y0b + (size_t)gr*64 + 32 + quad*8);
    // bn0 + relu per channel
    bf16x8 a0, a1;
    {
        const float* A = bnab0 + quad*8;
        const float* S = bnab0 + 64 + quad*8;
#pragma unroll
        for (int j = 0; j < 8; ++j) {
            float f = ubf((unsigned short)raw0[j]);
            a0[j] = (short)bf16u(fmaxf(fmaf(A[j], f, S[j]), 0.f));
        }
        const float* A2 = bnab0 + 32 + quad*8;
        const float* S2 = bnab0 + 96 + quad*8;
#pragma unroll
        for (int j = 0; j < 8; ++j) {
            float f = ubf((unsigned short)raw1[j]);
            a1[j] = (short)bf16u(fmaxf(fmaf(A2[j], f, S2[j]), 0.f));
        }
    }
    __syncthreads();

    f32x4 acc[4];
#pragma unroll
    for (int ct = 0; ct < 4; ++ct) {
        float bv = cb1[ct*16 + mrow];
        acc[ct] = (f32x4){bv, bv, bv, bv};
    }
#pragma unroll
    for (int ct = 0; ct < 4; ++ct) {
        bf16x8 b0 = *(const bf16x8*)(W1B + (ct*16 + mrow)*72 + quad*8);
        bf16x8 b1 = *(const bf16x8*)(W1B + (ct*16 + mrow)*72 + 32 + quad*8);
        acc[ct] = __builtin_amdgcn_mfma_f32_16x16x32_bf16(a0, b0, acc[ct], 0, 0, 0);
        acc[ct] = __builtin_amdgcn_mfma_f32_16x16x32_bf16(a1, b1, acc[ct], 0, 0, 0);
    }
#pragma unroll
    for (int ct = 0; ct < 4; ++ct) {
        f32x4 v = acc[ct];
        float s = (v.x + v.y) + (v.z + v.w);
        float q = (v.x*v.x + v.y*v.y) + (v.z*v.z + v.w*v.w);
        atomicAdd(&sAcc[ct*16 + mrow], s);
        atomicAdd(&qAcc[ct*16 + mrow], q);
    }
    const int rbase = wv*16 + quad*4;
#pragma unroll
    for (int ct = 0; ct < 4; ++ct) {
        int col = ct*16 + mrow;
        f32x4 v = acc[ct];
        STG[(rbase+0)*72 + col] = (unsigned short)bf16u(v.x);
        STG[(rbase+1)*72 + col] = (unsigned short)bf16u(v.y);
        STG[(rbase+2)*72 + col] = (unsigned short)bf16u(v.z);
        STG[(rbase+3)*72 + col] = (unsigned short)bf16u(v.w);
    }
    __syncthreads();
    for (int i = tid; i < 512; i += 256) {
        int r = i >> 3, c8 = i & 7;
        *(uint4*)(y1b + (size_t)(r0 + r)*64 + c8*8) = *(const uint4*)(STG + r*72 + c8*8);
    }
    if (tid < 64) { atomicAdd(statS + tid, sAcc[tid]); atomicAdd(statQ + tid, qAcc[tid]); }
}

// pass2: stream Y1, bn1+relu, L2 MFMA (128 out), stats2 + packed extrema.
__global__ __launch_bounds__(256) void pass2_kernel(
    const unsigned short* __restrict__ y1b, const unsigned short* __restrict__ wt2b,
    const float* __restrict__ cb2, const float* __restrict__ bnab1,
    float* __restrict__ statS, float* __restrict__ statQ,
    unsigned int* __restrict__ packed)
{
    __shared__ __align__(16) unsigned short W2B[128*72];
    __shared__ float sAcc[128], qAcc[128];
    __shared__ float mxs[4*128], mns[4*128];
    const int tid = threadIdx.x;
    const int r0 = blockIdx.x * 64;
    const int lane = tid & 63, wv = tid >> 6;
    const int mrow = lane & 15, quad = lane >> 4;

    {
        const uint4* s = (const uint4*)wt2b;
        for (int i = tid; i < 1024; i += 256) {
            int r = i >> 3, ch = i & 7;
            *(uint4*)(W2B + r*72 + ch*8) = s[i];
        }
    }
    if (tid < 128) { sAcc[tid] = 0.f; qAcc[tid] = 0.f; }

    const int gr = r0 + wv*16 + mrow;
    bf16x8 raw0 = *(const bf16x8*)(y1b + (size_t)gr*64 + quad*8);
    bf16x8 raw1 = *(const bf16x8*)(y1b + (size_t)gr*64 + 32 + quad*8);
    bf16x8 a0, a1;
    {
        const float* A = bnab1 + quad*8;
        const float* S = bnab1 + 64 + quad*8;
#pragma unroll
        for (int j = 0; j < 8; ++j) {
            float f = ubf((unsigned short)raw0[j]);
            a0[j] = (short)bf16u(fmaxf(fmaf(A[j], f, S[j]), 0.f));
        }
        const float* A2 = bnab1 + 32 + quad*8;
        const float* S2 = bnab1 + 96 + quad*8;
#pragma unroll
        for (int j = 0; j < 8; ++j) {
            float f = ubf((unsigned short)raw1[j]);
            a1[j] = (short)bf16u(fmaxf(fmaf(A2[j], f, S2[j]), 0.f));
        }
    }
    __syncthreads();

    f32x4 acc[8];
#pragma unroll
    for (int ct = 0; ct < 8; ++ct) {
        float bv = cb2[ct*16 + mrow];
        acc[ct] = (f32x4){bv, bv, bv, bv};
    }
#pragma unroll
    for (int ct = 0; ct < 8; ++ct) {
        bf16x8 b0 = *(const bf16x8*)(W2B + (ct*16 + mrow)*72 + quad*8);
        bf16x8 b1 = *(const bf16x8*)(W2B + (ct*16 + mrow)*72 + 32 + quad*8);
        acc[ct] = __builtin_amdgcn_mfma_f32_16x16x32_bf16(a0, b0, acc[ct], 0, 0, 0);
        acc[ct] = __builtin_amdgcn_mfma_f32_16x16x32_bf16(a1, b1, acc[ct], 0, 0, 0);
    }
#pragma unroll
    for (int ct = 0; ct < 8; ++ct) {
        f32x4 v = acc[ct];
        float s = (v.x + v.y) + (v.z + v.w);
        float q = (v.x*v.x + v.y*v.y) + (v.z*v.z + v.w*v.w);
        atomicAdd(&sAcc[ct*16 + mrow], s);
        atomicAdd(&qAcc[ct*16 + mrow], q);
    }
#pragma unroll
    for (int ct = 0; ct < 8; ++ct) {
        f32x4 v = acc[ct];
        float mx = fmaxf(fmaxf(v.x, v.y), fmaxf(v.z, v.w));
        float mn = fminf(fminf(v.x, v.y), fminf(v.z, v.w));
        { float o = __shfl_xor(mx, 16); mx = fmaxf(mx, o); }
        { float o = __shfl_xor(mn, 16); mn = fminf(mn, o); }
        { float o = __shfl_xor(mx, 32); mx = fmaxf(mx, o); }
        { float o = __shfl_xor(mn, 32); mn = fminf(mn, o); }
        if (quad == 0) {
            mxs[wv*128 + ct*16 + mrow] = mx;
            mns[wv*128 + ct*16 + mrow] = mn;
        }
    }
    __syncthreads();
    {
        int g = tid >> 7, c = tid & 127;
        float mx = fmaxf(mxs[(2*g)*128 + c], mxs[(2*g+1)*128 + c]);
        float mn = fminf(mns[(2*g)*128 + c], mns[(2*g+1)*128 + c]);
        packed[(size_t)(blockIdx.x*2 + g)*128 + c] = (bf16u(mx) << 16) | bf16u(mn);
    }
    if (tid < 128) { atomicAdd(statS + tid, sAcc[tid]); atomicAdd(statQ + tid, qAcc[tid]); }
}

// ================== FALLBACK PATH (recompute, round-5 verified; gather
// mapping updated for features-first weight layout) ==================
template<int DEPTH>
__global__ __launch_bounds__(256) void mlp_pass(
    const float* __restrict__ xyz, const float* __restrict__ points,
    const float* __restrict__ nxw, const int* __restrict__ kidx,
    const unsigned short* __restrict__ wt0b, const unsigned short* __restrict__ wt1b,
    const unsigned short* __restrict__ wt2b,
    const float* __restrict__ cb0, const float* __restrict__ cb1,
    const float* __restrict__ cb2,
    const float* __restrict__ bnab0, const float* __restrict__ bnab1,
    float* __restrict__ statS, float* __restrict__ statQ,
    unsigned int* __restrict__ packed)
{
    __shared__ __align__(16) unsigned short XsB[64*104];
    __shared__ __align__(16) unsigned short W0B[64*104];
    __shared__ __align__(16) unsigned short W1B[(DEPTH>=2) ? 64*72 : 8];
    __shared__ __align__(16) unsigned short W2B[(DEPTH==3) ? 128*72 : 8];
    __shared__ __align__(16) unsigned short Gb [(DEPTH>=2) ? 64*72 : 8];
    __shared__ float sAcc[128], qAcc[128];
    __shared__ float mxs[(DEPTH==3) ? 4*128 : 1];
    __shared__ float mns[(DEPTH==3) ? 4*128 : 1];

    const int tid = threadIdx.x;
    const int r0 = blockIdx.x * 64;
    const int lane = tid & 63, wv = tid >> 6;
    const int mrow = lane & 15, quad = lane >> 4;

    {
        const uint4* s = (const uint4*)wt0b;
        for (int i = tid; i < 768; i += 256) {
            int r = i / 12, ch = i - r*12;
            *(uint4*)(W0B + r*104 + ch*8) = s[i];
        }
    }
    if constexpr (DEPTH >= 2) {
        const uint4* s = (const uint4*)wt1b;
        for (int i = tid; i < 512; i += 256) {
            int r = i >> 3, ch = i & 7;
            *(uint4*)(W1B + r*72 + ch*8) = s[i];
        }
    }
    if constexpr (DEPTH == 3) {
        const uint4* s = (const uint4*)wt2b;
        for (int i = tid; i < 1024; i += 256) {
            int r = i >> 3, ch = i & 7;
            *(uint4*)(W2B + r*72 + ch*8) = s[i];
        }
    }
    if (tid < 128) { sAcc[tid] = 0.f; qAcc[tid] = 0.f; }

    // gather (features-first: c<64 feat, 64..66 rel, 67..95 zero)
    for (int i = tid; i < 64*96; i += 256) {
        int r = i / 96, c = i - r*96;
        int gr = r0 + r;
        int q = gr >> 5;
        int n = kidx[gr];
        int bb = q >> 10;
        float v = 0.f;
        if (c < 64)      v = points[((size_t)(bb*N_ + n))*64 + c];
        else if (c < 67) v = xyz[((size_t)(bb*N_ + n))*3 + (c-64)] - nxw[q*3 + (c-64)];
        XsB[r*104 + c] = (unsigned short)bf16u(v);
    }
    __syncthreads();

    const int arow = wv*16 + mrow;
    f32x4 acc0[4];
#pragma unroll
    for (int ct = 0; ct < 4; ++ct) {
        float bv = cb0[ct*16 + mrow];
        acc0[ct] = (f32x4){bv, bv, bv, bv};
    }
#pragma unroll
    for (int kk = 0; kk < 96; kk += 32) {
        bf16x8 a = *(const bf16x8*)(XsB + arow*104 + kk + quad*8);
#pragma unroll
        for (int ct = 0; ct < 4; ++ct) {
            bf16x8 b = *(const bf16x8*)(W0B + (ct*16 + mrow)*104 + kk + quad*8);
            acc0[ct] = __builtin_amdgcn_mfma_f32_16x16x32_bf16(a, b, acc0[ct], 0, 0, 0);
        }
    }

    if constexpr (DEPTH == 1) {
#pragma unroll
        for (int ct = 0; ct < 4; ++ct) {
            f32x4 v = acc0[ct];
            float s = (v.x + v.y) + (v.z + v.w);
            float q = (v.x*v.x + v.y*v.y) + (v.z*v.z + v.w*v.w);
            atomicAdd(&sAcc[ct*16 + mrow], s);
            atomicAdd(&qAcc[ct*16 + mrow], q);
        }
        __syncthreads();
        if (tid < 64) { atomicAdd(statS + tid, sAcc[tid]); atomicAdd(statQ + tid, qAcc[tid]); }
        return;
    } else {
        const int rbase = wv*16 + quad*4;
#pragma unroll
        for (int ct = 0; ct < 4; ++ct) {
            int col = ct*16 + mrow;
            float a = bnab0[col], sh = bnab0[64 + col];
            f32x4 v = acc0[ct];
            Gb[(rbase+0)*72 + col] = (unsigned short)bf16u(fmaxf(fmaf(a, v.x, sh), 0.f));
            Gb[(rbase+1)*72 + col] = (unsigned short)bf16u(fmaxf(fmaf(a, v.y, sh), 0.f));
            Gb[(rbase+2)*72 + col] = (unsigned short)bf16u(fmaxf(fmaf(a, v.z, sh), 0.f));
            Gb[(rbase+3)*72 + col] = (unsigned short)bf16u(fmaxf(fmaf(a, v.w, sh), 0.f));
        }
        f32x4 acc1[4];
#pragma unroll
        for (int ct = 0; ct < 4; ++ct) {
            float bv = cb1[ct*16 + mrow];
            acc1[ct] = (f32x4){bv, bv, bv, bv};
        }
#pragma unroll
        for (int kk = 0; kk < 64; kk += 32) {
            bf16x8 a = *(const bf16x8*)(Gb + arow*72 + kk + quad*8);
#pragma unroll
            for (int ct = 0; ct < 4; ++ct) {
                bf16x8 b = *(const bf16x8*)(W1B + (ct*16 + mrow)*72 + kk + quad*8);
                acc1[ct] = __builtin_amdgcn_mfma_f32_16x16x32_bf16(a, b, acc1[ct], 0, 0, 0);
            }
        }
        if constexpr (DEPTH == 2) {
#pragma unroll
            for (int ct = 0; ct < 4; ++ct) {
                f32x4 v = acc1[ct];
                float s = (v.x + v.y) + (v.z + v.w);
                float q = (v.x*v.x + v.y*v.y) + (v.z*v.z + v.w*v.w);
                atomicAdd(&sAcc[ct*16 + mrow], s);
                atomicAdd(&qAcc[ct*16 + mrow], q);
            }
            __syncthreads();
            if (tid < 64) { atomicAdd(statS + tid, sAcc[tid]); atomicAdd(statQ + tid, qAcc[tid]); }
            return;
        } else {
#pragma unroll
            for (int ct = 0; ct < 4; ++ct) {
                int col = ct*16 + mrow;
                float a = bnab1[col], sh = bnab1[64 + col];
                f32x4 v = acc1[ct];
                Gb[(rbase+0)*72 + col] = (unsigned short)bf16u(fmaxf(fmaf(a, v.x, sh), 0.f));
                Gb[(rbase+1)*72 + col] = (unsigned short)bf16u(fmaxf(fmaf(a, v.y, sh), 0.f));
                Gb[(rbase+2)*72 + col] = (unsigned short)bf16u(fmaxf(fmaf(a, v.z, sh), 0.f));
                Gb[(rbase+3)*72 + col] = (unsigned short)bf16u(fmaxf(fmaf(a, v.w, sh), 0.f));
            }
            f32x4 acc2[8];
#pragma unroll
            for (int ct = 0; ct < 8; ++ct) {
                float bv = cb2[ct*16 + mrow];
                acc2[ct] = (f32x4){bv, bv, bv, bv};
            }
#pragma unroll
            for (int kk = 0; kk < 64; kk += 32) {
                bf16x8 a = *(const bf16x8*)(Gb + arow*72 + kk + quad*8);
#pragma unroll
                for (int ct = 0; ct < 8; ++ct) {
                    bf16x8 b = *(const bf16x8*)(W2B + (ct*16 + mrow)*72 + kk + quad*8);
                    acc2[ct] = __builtin_amdgcn_mfma_f32_16x16x32_bf16(a, b, acc2[ct], 0, 0, 0);
                }
            }
#pragma unroll
            for (int ct = 0; ct < 8; ++ct) {
                f32x4 v = acc2[ct];
                float s = (v.x + v.y) + (v.z + v.w);
                float q = (v.x*v.x + v.y*v.y) + (v.z*v.z + v.w*v.w);
                atomicAdd(&sAcc[ct*16 + mrow], s);
                atomicAdd(&qAcc[ct*16 + mrow], q);
            }
#pragma unroll
            for (int ct = 0; ct < 8; ++ct) {
                f32x4 v = acc2[ct];
                float mx = fmaxf(fmaxf(v.x, v.y), fmaxf(v.z, v.w));
                float mn = fminf(fminf(v.x, v.y), fminf(v.z, v.w));
                { float o = __shfl_xor(mx, 16); mx = fmaxf(mx, o); }
                { float o = __shfl_xor(mn, 16); mn = fminf(mn, o); }
                { float o = __shfl_xor(mx, 32); mx = fmaxf(mx, o); }
                { float o = __shfl_xor(mn, 32); mn = fminf(mn, o); }
                if (quad == 0) {
                    mxs[wv*128 + ct*16 + mrow] = mx;
                    mns[wv*128 + ct*16 + mrow] = mn;
                }
            }
            __syncthreads();
            {
                int g = tid >> 7, c = tid & 127;
                float mx = fmaxf(mxs[(2*g)*128 + c], mxs[(2*g+1)*128 + c]);
                float mn = fminf(mns[(2*g)*128 + c], mns[(2*g+1)*128 + c]);
                packed[(size_t)(blockIdx.x*2 + g)*128 + c] = (bf16u(mx) << 16) | bf16u(mn);
            }
            if (tid < 128) { atomicAdd(statS + tid, sAcc[tid]); atomicAdd(statQ + tid, qAcc[tid]); }
        }
    }
}

// ---------------- BN finalize ----------------
template<int COUT>
__global__ void bn_finalize(const float* __restrict__ stat_s, const float* __restrict__ stat_q,
                            const float* __restrict__ gamma, const float* __restrict__ beta,
                            float* __restrict__ bnab) {
    int c = threadIdx.x;
    if (c < COUT) {
        const float inv_n = 1.f / (float)RTOT;
        float mu  = stat_s[c] * inv_n;
        float var = stat_q[c] * inv_n - mu*mu;
        float inv = 1.f / sqrtf(var + EPSF);
        float a = gamma[c] * inv;
        bnab[c] = a;
        bnab[COUT + c] = beta[c] - mu * a;
    }
}

// ---------------- final: BN2+ReLU on pooled extrema ----------------
__global__ __launch_bounds__(256) void final_out(const unsigned int* __restrict__ packed,
                                                 const float* __restrict__ bnab2,
                                                 float* __restrict__ out_np) {
    int idx = blockIdx.x*256 + threadIdx.x;
    int c = idx & 127;
    float a = bnab2[c], sh = bnab2[128 + c];
    unsigned p = packed[idx];
    float mx = __uint_as_float(p & 0xFFFF0000u);
    float mn = __uint_as_float(p << 16);
    float x = (a >= 0.f) ? mx : mn;
    out_np[idx] = fmaxf(fmaf(a, x, sh), 0.f);
}

extern "C" void kernel_launch(void* const* d_in, const int* in_sizes, int n_in,
                              void* d_out, int out_size, void* d_ws, size_t ws_size,
                              hipStream_t stream) {
    const float* xyz    = (const float*)d_in[0];
    const float* points = (const float*)d_in[1];
    const float* W0 = (const float*)d_in[2];
    const float* b0 = (const float*)d_in[3];
    const float* g0 = (const float*)d_in[4];
    const float* be0= (const float*)d_in[5];
    const float* W1 = (const float*)d_in[6];
    const float* b1 = (const float*)d_in[7];
    const float* g1 = (const float*)d_in[8];
    const float* be1= (const float*)d_in[9];
    const float* W2 = (const float*)d_in[10];
    const float* b2 = (const float*)d_in[11];
    const float* g2 = (const float*)d_in[12];
    const float* be2= (const float*)d_in[13];

    float* ws  = (float*)d_ws;
    float* out = (float*)d_out;
    float* out_newxyz = out;                        // 49152
    float* out_np     = out + 49152;                // 2097152
    float* out_fpsidx = out + 49152 + 2097152;      // 16384

    unsigned short* wt0b = (unsigned short*)(ws + WT0B_OFF);
    unsigned short* wt1b = (unsigned short*)(ws + WT1B_OFF);
    unsigned short* wt2b = (unsigned short*)(ws + WT2B_OFF);
    float* s0 = ws + ST_OFF;        float* q0 = s0 + 64;
    float* s1 = q0 + 64;            float* q1 = s1 + 64;
    float* s2 = q1 + 64;            float* q2 = s2 + 128;
    float* bnab0 = ws + BN_OFF;     float* bnab1 = bnab0 + 128;  float* bnab2 = bnab1 + 128;
    float* nxw   = ws + NXW_OFF;
    int*   kidx  = (int*)(ws + KIDX_OFF);
    unsigned int* packed = (unsigned int*)(ws + PK_OFF);
    unsigned short* y0b = (unsigned short*)(ws + Y0B_OFF);
    unsigned short* y1b = (unsigned short*)(ws + Y1B_OFF);

    prep_kernel<<<1, 256, 0, stream>>>(W0, W1, W2, ws);
    fps_kernel<<<B_, 256, 0, stream>>>(xyz, out_newxyz, out_fpsidx, nxw);
    knn_kernel<<<(B_*M_)/4, 256, 0, stream>>>(xyz, nxw, kidx);

    if (ws_size >= WS_NEED_BYTES) {
        pass0_kernel<<<RTOT/64, 256, 0, stream>>>(xyz, points, nxw, kidx, wt0b, b0, s0, q0, y0b);
        bn_finalize<64><<<1, 64, 0, stream>>>(s0, q0, g0, be0, bnab0);
        pass1_kernel<<<RTOT/64, 256, 0, stream>>>(y0b, wt1b, b1, bnab0, s1, q1, y1b);
        bn_finalize<64><<<1, 64, 0, stream>>>(s1, q1, g1, be1, bnab1);
        pass2_kernel<<<RTOT/64, 256, 0, stream>>>(y1b, wt2b, b2, bnab1, s2, q2, packed);
        bn_finalize<128><<<1, 128, 0, stream>>>(s2, q2, g2, be2, bnab2);
    } else {
        mlp_pass<1><<<RTOT/64, 256, 0, stream>>>(xyz, points, nxw, kidx, wt0b, wt1b, wt2b,
            b0, b1, b2, nullptr, nullptr, s0, q0, nullptr);
        bn_finalize<64><<<1, 64, 0, stream>>>(s0, q0, g0, be0, bnab0);
        mlp_pass<2><<<RTOT/64, 256, 0, stream>>>(xyz, points, nxw, kidx, wt0b, wt1b, wt2b,
            b0, b1, b2, bnab0, nullptr, s1, q1, nullptr);
        bn_finalize<64><<<1, 64, 0, stream>>>(s1, q1, g1, be1, bnab1);
        mlp_pass<3><<<RTOT/64, 256, 0, stream>>>(xyz, points, nxw, kidx, wt0b, wt1b, wt2b,
            b0, b1, b2, bnab0, bnab1, s2, q2, packed);
        bn_finalize<128><<<1, 128, 0, stream>>>(s2, q2, g2, be2, bnab2);
    }

    final_out<<<(B_*M_*128)/256, 256, 0, stream>>>(packed, bnab2, out_np);
}

// Round 7
// 1300.240 us; speedup vs baseline: 2.4446x; 1.4364x over previous
//
#include <hip/hip_runtime.h>
#include <math.h>

#define B_ 16
#define N_ 4096
#define D_ 64
#define M_ 1024
#define K_ 32
#define RTOT (B_*M_*K_)          // 524288 rows
#define EPSF 1e-5f

// ---------------- ws layout (float units)
#define WT0B_OFF  0              // bf16 W0 perm [64 out][96 k] = 3072 f
#define WT1B_OFF  3072           // bf16 [64][64] = 2048 f
#define WT2B_OFF  5120           // bf16 [128][64] = 4096 f
#define ST_OFF    9216           // fallback stats s/q = 512
#define BN_OFF    9728           // ab0[128] ab1[128] ab2[256] = 512
#define NXW_OFF   10240          // new_xyz f32 [16384*3]
#define KIDX_OFF  59392          // knn idx int [524288]
#define PK_OFF    583680         // packed bf16 (max,min) [16384*128] uint32
#define Y0B_OFF   2680832        // bf16 Y0 raw [524288*64] = 16777216 f
#define Y1B_OFF   19458048       // bf16 Y1 raw [524288*64] = 16777216 f
// stat buckets (fast path only): 64 buckets, s then q per layer
#define SB0_OFF   36235264       // [64][64]s + [64][64]q = 8192
#define SB1_OFF   (SB0_OFF + 8192)
#define SB2_OFF   (SB1_OFF + 8192)   // [64][128]s + [64][128]q = 16384
#define WS_FAST_BYTES ((unsigned long long)(SB2_OFF + 16384) * 4ull)

typedef __attribute__((ext_vector_type(8))) short bf16x8;
typedef __attribute__((ext_vector_type(4))) float f32x4;

__device__ inline unsigned bf16u(float x) {
    unsigned u = __float_as_uint(x);
    return (u + 0x7FFFu + ((u >> 16) & 1u)) >> 16;   // RN-even
}
__device__ inline float ubf(unsigned short h) {
    return __uint_as_float(((unsigned)h) << 16);
}

// ---------------- prep: zero stats (+buckets if fast), bf16 weights --------
__global__ void prep_kernel(const float* __restrict__ W0, const float* __restrict__ W1,
                            const float* __restrict__ W2, float* __restrict__ ws,
                            int zero_sb) {
    int tid = threadIdx.x;
    unsigned short* wt0b = (unsigned short*)(ws + WT0B_OFF);
    unsigned short* wt1b = (unsigned short*)(ws + WT1B_OFF);
    unsigned short* wt2b = (unsigned short*)(ws + WT2B_OFF);
    float* st = ws + ST_OFF;
    for (int i = tid; i < 512; i += 256) st[i] = 0.f;
    if (zero_sb) {
        float* sb = ws + SB0_OFF;
        for (int i = tid; i < 32768; i += 256) sb[i] = 0.f;
    }
    for (int i = tid; i < 64*96; i += 256) {
        int o = i / 96, k = i - o*96;
        float w = 0.f;
        if (k < 64)      w = W0[o*67 + 3 + k];
        else if (k < 67) w = W0[o*67 + (k - 64)];
        wt0b[i] = (unsigned short)bf16u(w);
    }
    for (int i = tid; i < 64*64; i += 256)  wt1b[i] = (unsigned short)bf16u(W1[i]);
    for (int i = tid; i < 128*64; i += 256) wt2b[i] = (unsigned short)bf16u(W2[i]);
}

// ---------------- FPS: unchanged (verified) ----------------
__global__ __launch_bounds__(256) void fps_kernel(const float* __restrict__ xyz,
                                                  float* __restrict__ out_newxyz,
                                                  float* __restrict__ out_fpsidx,
                                                  float* __restrict__ ws_newxyz) {
#pragma clang fp contract(off)
    __shared__ float4 pts[N_];
    __shared__ int selidx[M_];
    __shared__ unsigned long long red[2][4];
    const int b = blockIdx.x;
    const int tid = threadIdx.x;
    const int lane = tid & 63, wave = tid >> 6;
    const float* xb = xyz + (size_t)b * N_ * 3;
    for (int i = tid; i < N_; i += 256)
        pts[i] = make_float4(xb[i*3+0], xb[i*3+1], xb[i*3+2], 0.f);
    __syncthreads();
    float px[16], py[16], pz[16], dist[16];
#pragma unroll
    for (int j = 0; j < 16; ++j) {
        float4 p = pts[(tid << 4) + j];
        px[j] = p.x; py[j] = p.y; pz[j] = p.z;
        dist[j] = 3.4e38f;
    }
    int cur = N_/2;
    for (int t = 0; t < M_; ++t) {
        if (tid == (t & 255)) selidx[t] = cur;
        if (t == M_-1) break;
        float4 c4 = pts[cur];
        float cx = c4.x, cy = c4.y, cz = c4.z;
        float bm0 = -1.f, bm1 = -1.f, bm2 = -1.f, bm3 = -1.f;
        int bj0 = 0, bj1 = 4, bj2 = 8, bj3 = 12;
#pragma unroll
        for (int j = 0; j < 4; ++j) {
            {
                float dx = px[j]-cx, dy = py[j]-cy, dz = pz[j]-cz;
                float a = dx*dx, b2 = dy*dy, c2 = dz*dz;
                float d = (a + b2) + c2;
                float nd = fminf(dist[j], d); dist[j] = nd;
                bool bt = nd > bm0; bm0 = bt ? nd : bm0; bj0 = bt ? j : bj0;
            }
            {
                int k = j + 4;
                float dx = px[k]-cx, dy = py[k]-cy, dz = pz[k]-cz;
                float a = dx*dx, b2 = dy*dy, c2 = dz*dz;
                float d = (a + b2) + c2;
                float nd = fminf(dist[k], d); dist[k] = nd;
                bool bt = nd > bm1; bm1 = bt ? nd : bm1; bj1 = bt ? k : bj1;
            }
            {
                int k = j + 8;
                float dx = px[k]-cx, dy = py[k]-cy, dz = pz[k]-cz;
                float a = dx*dx, b2 = dy*dy, c2 = dz*dz;
                float d = (a + b2) + c2;
                float nd = fminf(dist[k], d); dist[k] = nd;
                bool bt = nd > bm2; bm2 = bt ? nd : bm2; bj2 = bt ? k : bj2;
            }
            {
                int k = j + 12;
                float dx = px[k]-cx, dy = py[k]-cy, dz = pz[k]-cz;
                float a = dx*dx, b2 = dy*dy, c2 = dz*dz;
                float d = (a + b2) + c2;
                float nd = fminf(dist[k], d); dist[k] = nd;
                bool bt = nd > bm3; bm3 = bt ? nd : bm3; bj3 = bt ? k : bj3;
            }
        }
        float bv = bm0; int bj = bj0;
        if (bm1 > bv) { bv = bm1; bj = bj1; }
        if (bm2 > bv) { bv = bm2; bj = bj2; }
        if (bm3 > bv) { bv = bm3; bj = bj3; }
        unsigned mybits = __float_as_uint(bv);
        unsigned vr = mybits;
        { unsigned o = (unsigned)__builtin_amdgcn_update_dpp((int)vr,(int)vr,0x121,0xF,0xF,false); if (o > vr) vr = o; }
        { unsigned o = (unsigned)__builtin_amdgcn_update_dpp((int)vr,(int)vr,0x122,0xF,0xF,false); if (o > vr) vr = o; }
        { unsigned o = (unsigned)__builtin_amdgcn_update_dpp((int)vr,(int)vr,0x124,0xF,0xF,false); if (o > vr) vr = o; }
        { unsigned o = (unsigned)__builtin_amdgcn_update_dpp((int)vr,(int)vr,0x128,0xF,0xF,false); if (o > vr) vr = o; }
        unsigned r0 = (unsigned)__builtin_amdgcn_readlane((int)vr, 0);
        unsigned r1 = (unsigned)__builtin_amdgcn_readlane((int)vr, 16);
        unsigned r2 = (unsigned)__builtin_amdgcn_readlane((int)vr, 32);
        unsigned r3 = (unsigned)__builtin_amdgcn_readlane((int)vr, 48);
        unsigned m01 = (r0 > r1) ? r0 : r1;
        unsigned m23 = (r2 > r3) ? r2 : r3;
        unsigned vmax = (m01 > m23) ? m01 : m23;
        unsigned long long mask = __ballot(mybits == vmax);
        int wl = (int)__builtin_ctzll(mask);
        int gidx = (tid << 4) + bj;
        int sel = __builtin_amdgcn_readlane(gidx, wl);
        unsigned long long key = ((unsigned long long)vmax << 32) | (unsigned)(~sel);
        int buf = t & 1;
        if (lane == 0) red[buf][wave] = key;
        __syncthreads();
        unsigned long long k0 = red[buf][0], k1 = red[buf][1];
        unsigned long long k2 = red[buf][2], k3 = red[buf][3];
        unsigned long long km01 = (k0 > k1) ? k0 : k1;
        unsigned long long km23 = (k2 > k3) ? k2 : k3;
        unsigned long long km   = (km01 > km23) ? km01 : km23;
        cur = (int)((~(unsigned)km) & (N_-1));
    }
    __syncthreads();
    for (int i = tid; i < M_; i += 256) {
        int c = selidx[i];
        out_fpsidx[b*M_ + i] = (float)c;
        float4 p = pts[c];
        size_t o3 = (size_t)(b*M_ + i)*3;
        out_newxyz[o3+0] = p.x; out_newxyz[o3+1] = p.y; out_newxyz[o3+2] = p.z;
        ws_newxyz[o3+0] = p.x;  ws_newxyz[o3+1] = p.y;  ws_newxyz[o3+2] = p.z;
    }
}

// ---------------- kNN v2: lazy top-2 + consumed bitmask ----------------
// Phase 1 tracks per-lane (m1,k1,m2,k2). On win: promote m2 in O(1);
// full (bitmask-filtered) rescan only on a lane's 2nd+ win. No val[] mutation.
// Tie semantics identical to v1: strict < keeps lowest k; u64-min key
// (orderable dist << 32 | point index) picks lowest index on value ties.
__global__ __launch_bounds__(256) void knn_kernel(const float* __restrict__ xyz,
                                                  const float* __restrict__ ws_newxyz,
                                                  int* __restrict__ knn_idx) {
#pragma clang fp contract(off)
    const int lane = threadIdx.x & 63;
    const int q = blockIdx.x * 4 + (threadIdx.x >> 6);
    const int b = q >> 10;
    const float* xb = xyz + (size_t)b * N_ * 3;
    float qx = ws_newxyz[q*3+0], qy = ws_newxyz[q*3+1], qz = ws_newxyz[q*3+2];
    float qq = qx*qx + qy*qy; qq = qq + qz*qz;
    float val[64];
    float m1 = 3.4e38f, m2 = 3.4e38f; int k1 = 0, k2 = 0;
#pragma unroll
    for (int k = 0; k < 64; ++k) {
        int n = (k<<6) + lane;
        float x = xb[n*3+0], y = xb[n*3+1], z = xb[n*3+2];
        float pp = x*x + y*y; pp = pp + z*z;
        float dot = qx*x + qy*y; dot = dot + qz*z;
        float d = (qq + pp) - 2.0f*dot;
        val[k] = d;
        if (d < m1)      { m2 = m1; k2 = k1; m1 = d; k1 = k; }
        else if (d < m2) { m2 = d; k2 = k; }
    }
    unsigned long long consumed = 0ull;
    bool has2 = true;
    unsigned int myOut = 0;
    for (int r = 0; r < 32; ++r) {
        unsigned int u = __float_as_uint(m1);
        u = (u & 0x80000000u) ? ~u : (u | 0x80000000u);   // orderable key
        unsigned long long pk = ((unsigned long long)u << 32) | (unsigned)(lane + (k1<<6));
#pragma unroll
        for (int off = 32; off > 0; off >>= 1) {
            unsigned long long o = __shfl_xor(pk, off);
            pk = (o < pk) ? o : pk;
        }
        unsigned g = (unsigned)pk;
        if (lane == r) myOut = g;
        if (lane == (int)(g & 63u)) {
            consumed |= (1ull << k1);
            if (has2) { m1 = m2; k1 = k2; has2 = false; }
            else {
                m1 = 3.4e38f; k1 = 0;
#pragma unroll
                for (int k = 0; k < 64; ++k) {
                    bool ok = !((consumed >> k) & 1ull) && (val[k] < m1);
                    m1 = ok ? val[k] : m1;
                    k1 = ok ? k : k1;
                }
            }
        }
    }
    if (lane < 32) knn_idx[q*32 + lane] = (int)myOut;
}

// ================== FAST PATH (stored intermediates, bucketed stats) =======
// pass0: gather X0, L0 MFMA, store raw Y0 bf16, stats0 -> bucket blockIdx&63.
__global__ __launch_bounds__(256) void pass0_kernel(
    const float* __restrict__ xyz, const float* __restrict__ points,
    const float* __restrict__ nxw, const int* __restrict__ kidx,
    const unsigned short* __restrict__ wt0b, const float* __restrict__ cb0,
    float* __restrict__ sb,           // [64][64]s + [64][64]q
    unsigned short* __restrict__ y0b)
{
    __shared__ __align__(16) unsigned short XsB[64*104];
    __shared__ __align__(16) unsigned short W0B[64*104];   // reused as store stage
    __shared__ int sidx[64];
    __shared__ float sAcc[64], qAcc[64];
    const int tid = threadIdx.x;
    const int r0 = blockIdx.x * 64;
    const int lane = tid & 63, wv = tid >> 6;
    const int mrow = lane & 15, quad = lane >> 4;

    if (tid < 64) { sidx[tid] = kidx[r0 + tid]; sAcc[tid] = 0.f; qAcc[tid] = 0.f; }
    {
        const uint4* s = (const uint4*)wt0b;
        for (int i = tid; i < 768; i += 256) {
            int r = i / 12, ch = i - r*12;
            *(uint4*)(W0B + r*104 + ch*8) = s[i];
        }
    }
    __syncthreads();

    {
        int row = tid >> 2, q4 = tid & 3;
        int gr = r0 + row;
        int qq = gr >> 5, bb = qq >> 10;
        int n = sidx[row];
        const float4* src = (const float4*)(points + ((size_t)(bb*N_ + n))*64 + q4*16);
        float4 f0 = src[0], f1 = src[1], f2 = src[2], f3 = src[3];
        uint4 u0, u1;
        u0.x = bf16u(f0.x) | (bf16u(f0.y) << 16);
        u0.y = bf16u(f0.z) | (bf16u(f0.w) << 16);
        u0.z = bf16u(f1.x) | (bf16u(f1.y) << 16);
        u0.w = bf16u(f1.z) | (bf16u(f1.w) << 16);
        u1.x = bf16u(f2.x) | (bf16u(f2.y) << 16);
        u1.y = bf16u(f2.z) | (bf16u(f2.w) << 16);
        u1.z = bf16u(f3.x) | (bf16u(f3.y) << 16);
        u1.w = bf16u(f3.z) | (bf16u(f3.w) << 16);
        *(uint4*)(XsB + row*104 + q4*16)     = u0;
        *(uint4*)(XsB + row*104 + q4*16 + 8) = u1;
        uint4 z;
        if (q4 == 0) {
            float rx = xyz[((size_t)(bb*N_ + n))*3 + 0] - nxw[qq*3 + 0];
            float ry = xyz[((size_t)(bb*N_ + n))*3 + 1] - nxw[qq*3 + 1];
            float rz = xyz[((size_t)(bb*N_ + n))*3 + 2] - nxw[qq*3 + 2];
            z.x = bf16u(rx) | (bf16u(ry) << 16);
            z.y = bf16u(rz);
            z.z = 0; z.w = 0;
        } else { z.x = 0; z.y = 0; z.z = 0; z.w = 0; }
        *(uint4*)(XsB + row*104 + 64 + q4*8) = z;
    }
    __syncthreads();

    const int arow = wv*16 + mrow;
    f32x4 acc0[4];
#pragma unroll
    for (int ct = 0; ct < 4; ++ct) {
        float bv = cb0[ct*16 + mrow];
        acc0[ct] = (f32x4){bv, bv, bv, bv};
    }
#pragma unroll
    for (int kk = 0; kk < 96; kk += 32) {
        bf16x8 a = *(const bf16x8*)(XsB + arow*104 + kk + quad*8);
#pragma unroll
        for (int ct = 0; ct < 4; ++ct) {
            bf16x8 b = *(const bf16x8*)(W0B + (ct*16 + mrow)*104 + kk + quad*8);
            acc0[ct] = __builtin_amdgcn_mfma_f32_16x16x32_bf16(a, b, acc0[ct], 0, 0, 0);
        }
    }
#pragma unroll
    for (int ct = 0; ct < 4; ++ct) {
        f32x4 v = acc0[ct];
        float s = (v.x + v.y) + (v.z + v.w);
        float q = (v.x*v.x + v.y*v.y) + (v.z*v.z + v.w*v.w);
        atomicAdd(&sAcc[ct*16 + mrow], s);
        atomicAdd(&qAcc[ct*16 + mrow], q);
    }
    __syncthreads();   // W0B reads done
    unsigned short* STG = W0B;
    const int rbase = wv*16 + quad*4;
#pragma unroll
    for (int ct = 0; ct < 4; ++ct) {
        int col = ct*16 + mrow;
        f32x4 v = acc0[ct];
        STG[(rbase+0)*72 + col] = (unsigned short)bf16u(v.x);
        STG[(rbase+1)*72 + col] = (unsigned short)bf16u(v.y);
        STG[(rbase+2)*72 + col] = (unsigned short)bf16u(v.z);
        STG[(rbase+3)*72 + col] = (unsigned short)bf16u(v.w);
    }
    __syncthreads();
    for (int i = tid; i < 512; i += 256) {
        int r = i >> 3, c8 = i & 7;
        *(uint4*)(y0b + (size_t)(r0 + r)*64 + c8*8) = *(const uint4*)(STG + r*72 + c8*8);
    }
    int bk = blockIdx.x & 63;
    if (tid < 64) {
        atomicAdd(sb + bk*64 + tid, sAcc[tid]);
        atomicAdd(sb + 4096 + bk*64 + tid, qAcc[tid]);
    }
}

// pass1: stream Y0, bn0+relu in-register, L1 MFMA, store raw Y1, stats1.
__global__ __launch_bounds__(256) void pass1_kernel(
    const unsigned short* __restrict__ y0b, const unsigned short* __restrict__ wt1b,
    const float* __restrict__ cb1, const float* __restrict__ bnab0,
    float* __restrict__ sb,
    unsigned short* __restrict__ y1b)
{
    __shared__ __align__(16) unsigned short W1B[64*72];
    __shared__ __align__(16) unsigned short STG[64*72];
    __shared__ float sAcc[64], qAcc[64];
    const int tid = threadIdx.x;
    const int r0 = blockIdx.x * 64;
    const int lane = tid & 63, wv = tid >> 6;
    const int mrow = lane & 15, quad = lane >> 4;

    {
        const uint4* s = (const uint4*)wt1b;
        for (int i = tid; i < 512; i += 256) {
            int r = i >> 3, ch = i & 7;
            *(uint4*)(W1B + r*72 + ch*8) = s[i];
        }
    }
    if (tid < 64) { sAcc[tid] = 0.f; qAcc[tid] = 0.f; }

    const int gr = r0 + wv*16 + mrow;
    bf16x8 raw0 = *(const bf16x8*)(y0b + (size_t)gr*64 + quad*8);
    bf16x8 raw1 = *(const bf16x8*)(y0b + (size_t)gr*64 + 32 + quad*8);
    bf16x8 a0, a1;
    {
        const float* A = bnab0 + quad*8;
        const float* S = bnab0 + 64 + quad*8;
#pragma unroll
        for (int j = 0; j < 8; ++j) {
            float f = ubf((unsigned short)raw0[j]);
            a0[j] = (short)bf16u(fmaxf(fmaf(A[j], f, S[j]), 0.f));
        }
        const float* A2 = bnab0 + 32 + quad*8;
        const float* S2 = bnab0 + 96 + quad*8;
#pragma unroll
        for (int j = 0; j < 8; ++j) {
            float f = ubf((unsigned short)raw1[j]);
            a1[j] = (short)bf16u(fmaxf(fmaf(A2[j], f, S2[j]), 0.f));
        }
    }
    __syncthreads();

    f32x4 acc[4];
#pragma unroll
    for (int ct = 0; ct < 4; ++ct) {
        float bv = cb1[ct*16 + mrow];
        acc[ct] = (f32x4){bv, bv, bv, bv};
    }
#pragma unroll
    for (int ct = 0; ct < 4; ++ct) {
        bf16x8 b0 = *(const bf16x8*)(W1B + (ct*16 + mrow)*72 + quad*8);
        bf16x8 b1 = *(const bf16x8*)(W1B + (ct*16 + mrow)*72 + 32 + quad*8);
        acc[ct] = __builtin_amdgcn_mfma_f32_16x16x32_bf16(a0, b0, acc[ct], 0, 0, 0);
        acc[ct] = __builtin_amdgcn_mfma_f32_16x16x32_bf16(a1, b1, acc[ct], 0, 0, 0);
    }
#pragma unroll
    for (int ct = 0; ct < 4; ++ct) {
        f32x4 v = acc[ct];
        float s = (v.x + v.y) + (v.z + v.w);
        float q = (v.x*v.x + v.y*v.y) + (v.z*v.z + v.w*v.w);
        atomicAdd(&sAcc[ct*16 + mrow], s);
        atomicAdd(&qAcc[ct*16 + mrow], q);
    }
    const int rbase = wv*16 + quad*4;
#pragma unroll
    for (int ct = 0; ct < 4; ++ct) {
        int col = ct*16 + mrow;
        f32x4 v = acc[ct];
        STG[(rbase+0)*72 + col] = (unsigned short)bf16u(v.x);
        STG[(rbase+1)*72 + col] = (unsigned short)bf16u(v.y);
        STG[(rbase+2)*72 + col] = (unsigned short)bf16u(v.z);
        STG[(rbase+3)*72 + col] = (unsigned short)bf16u(v.w);
    }
    __syncthreads();
    for (int i = tid; i < 512; i += 256) {
        int r = i >> 3, c8 = i & 7;
        *(uint4*)(y1b + (size_t)(r0 + r)*64 + c8*8) = *(const uint4*)(STG + r*72 + c8*8);
    }
    int bk = blockIdx.x & 63;
    if (tid < 64) {
        atomicAdd(sb + bk*64 + tid, sAcc[tid]);
        atomicAdd(sb + 4096 + bk*64 + tid, qAcc[tid]);
    }
}

// pass2: stream Y1, bn1+relu, L2 MFMA (128 out), stats2 + packed extrema.
__global__ __launch_bounds__(256) void pass2_kernel(
    const unsigned short* __restrict__ y1b, const unsigned short* __restrict__ wt2b,
    const float* __restrict__ cb2, const float* __restrict__ bnab1,
    float* __restrict__ sb,
    unsigned int* __restrict__ packed)
{
    __shared__ __align__(16) unsigned short W2B[128*72];
    __shared__ float sAcc[128], qAcc[128];
    __shared__ float mxs[4*128], mns[4*128];
    const int tid = threadIdx.x;
    const int r0 = blockIdx.x * 64;
    const int lane = tid & 63, wv = tid >> 6;
    const int mrow = lane & 15, quad = lane >> 4;

    {
        const uint4* s = (const uint4*)wt2b;
        for (int i = tid; i < 1024; i += 256) {
            int r = i >> 3, ch = i & 7;
            *(uint4*)(W2B + r*72 + ch*8) = s[i];
        }
    }
    if (tid < 128) { sAcc[tid] = 0.f; qAcc[tid] = 0.f; }

    const int gr = r0 + wv*16 + mrow;
    bf16x8 raw0 = *(const bf16x8*)(y1b + (size_t)gr*64 + quad*8);
    bf16x8 raw1 = *(const bf16x8*)(y1b + (size_t)gr*64 + 32 + quad*8);
    bf16x8 a0, a1;
    {
        const float* A = bnab1 + quad*8;
        const float* S = bnab1 + 64 + quad*8;
#pragma unroll
        for (int j = 0; j < 8; ++j) {
            float f = ubf((unsigned short)raw0[j]);
            a0[j] = (short)bf16u(fmaxf(fmaf(A[j], f, S[j]), 0.f));
        }
        const float* A2 = bnab1 + 32 + quad*8;
        const float* S2 = bnab1 + 96 + quad*8;
#pragma unroll
        for (int j = 0; j < 8; ++j) {
            float f = ubf((unsigned short)raw1[j]);
            a1[j] = (short)bf16u(fmaxf(fmaf(A2[j], f, S2[j]), 0.f));
        }
    }
    __syncthreads();

    f32x4 acc[8];
#pragma unroll
    for (int ct = 0; ct < 8; ++ct) {
        float bv = cb2[ct*16 + mrow];
        acc[ct] = (f32x4){bv, bv, bv, bv};
    }
#pragma unroll
    for (int ct = 0; ct < 8; ++ct) {
        bf16x8 b0 = *(const bf16x8*)(W2B + (ct*16 + mrow)*72 + quad*8);
        bf16x8 b1 = *(const bf16x8*)(W2B + (ct*16 + mrow)*72 + 32 + quad*8);
        acc[ct] = __builtin_amdgcn_mfma_f32_16x16x32_bf16(a0, b0, acc[ct], 0, 0, 0);
        acc[ct] = __builtin_amdgcn_mfma_f32_16x16x32_bf16(a1, b1, acc[ct], 0, 0, 0);
    }
#pragma unroll
    for (int ct = 0; ct < 8; ++ct) {
        f32x4 v = acc[ct];
        float s = (v.x + v.y) + (v.z + v.w);
        float q = (v.x*v.x + v.y*v.y) + (v.z*v.z + v.w*v.w);
        atomicAdd(&sAcc[ct*16 + mrow], s);
        atomicAdd(&qAcc[ct*16 + mrow], q);
    }
#pragma unroll
    for (int ct = 0; ct < 8; ++ct) {
        f32x4 v = acc[ct];
        float mx = fmaxf(fmaxf(v.x, v.y), fmaxf(v.z, v.w));
        float mn = fminf(fminf(v.x, v.y), fminf(v.z, v.w));
        { float o = __shfl_xor(mx, 16); mx = fmaxf(mx, o); }
        { float o = __shfl_xor(mn, 16); mn = fminf(mn, o); }
        { float o = __shfl_xor(mx, 32); mx = fmaxf(mx, o); }
        { float o = __shfl_xor(mn, 32); mn = fminf(mn, o); }
        if (quad == 0) {
            mxs[wv*128 + ct*16 + mrow] = mx;
            mns[wv*128 + ct*16 + mrow] = mn;
        }
    }
    __syncthreads();
    {
        int g = tid >> 7, c = tid & 127;
        float mx = fmaxf(mxs[(2*g)*128 + c], mxs[(2*g+1)*128 + c]);
        float mn = fminf(mns[(2*g)*128 + c], mns[(2*g+1)*128 + c]);
        packed[(size_t)(blockIdx.x*2 + g)*128 + c] = (bf16u(mx) << 16) | bf16u(mn);
    }
    int bk = blockIdx.x & 63;
    if (tid < 128) {
        atomicAdd(sb + bk*128 + tid, sAcc[tid]);
        atomicAdd(sb + 8192 + bk*128 + tid, qAcc[tid]);
    }
}

// ================== FALLBACK PATH (recompute, direct atomics) ==============
template<int DEPTH>
__global__ __launch_bounds__(256) void mlp_pass(
    const float* __restrict__ xyz, const float* __restrict__ points,
    const float* __restrict__ nxw, const int* __restrict__ kidx,
    const unsigned short* __restrict__ wt0b, const unsigned short* __restrict__ wt1b,
    const unsigned short* __restrict__ wt2b,
    const float* __restrict__ cb0, const float* __restrict__ cb1,
    const float* __restrict__ cb2,
    const float* __restrict__ bnab0, const float* __restrict__ bnab1,
    float* __restrict__ statS, float* __restrict__ statQ,
    unsigned int* __restrict__ packed)
{
    __shared__ __align__(16) unsigned short XsB[64*104];
    __shared__ __align__(16) unsigned short W0B[64*104];
    __shared__ __align__(16) unsigned short W1B[(DEPTH>=2) ? 64*72 : 8];
    __shared__ __align__(16) unsigned short W2B[(DEPTH==3) ? 128*72 : 8];
    __shared__ __align__(16) unsigned short Gb [(DEPTH>=2) ? 64*72 : 8];
    __shared__ float sAcc[128], qAcc[128];
    __shared__ float mxs[(DEPTH==3) ? 4*128 : 1];
    __shared__ float mns[(DEPTH==3) ? 4*128 : 1];

    const int tid = threadIdx.x;
    const int r0 = blockIdx.x * 64;
    const int lane = tid & 63, wv = tid >> 6;
    const int mrow = lane & 15, quad = lane >> 4;

    {
        const uint4* s = (const uint4*)wt0b;
        for (int i = tid; i < 768; i += 256) {
            int r = i / 12, ch = i - r*12;
            *(uint4*)(W0B + r*104 + ch*8) = s[i];
        }
    }
    if constexpr (DEPTH >= 2) {
        const uint4* s = (const uint4*)wt1b;
        for (int i = tid; i < 512; i += 256) {
            int r = i >> 3, ch = i & 7;
            *(uint4*)(W1B + r*72 + ch*8) = s[i];
        }
    }
    if constexpr (DEPTH == 3) {
        const uint4* s = (const uint4*)wt2b;
        for (int i = tid; i < 1024; i += 256) {
            int r = i >> 3, ch = i & 7;
            *(uint4*)(W2B + r*72 + ch*8) = s[i];
        }
    }
    if (tid < 128) { sAcc[tid] = 0.f; qAcc[tid] = 0.f; }

    for (int i = tid; i < 64*96; i += 256) {
        int r = i / 96, c = i - r*96;
        int gr = r0 + r;
        int q = gr >> 5;
        int n = kidx[gr];
        int bb = q >> 10;
        float v = 0.f;
        if (c < 64)      v = points[((size_t)(bb*N_ + n))*64 + c];
        else if (c < 67) v = xyz[((size_t)(bb*N_ + n))*3 + (c-64)] - nxw[q*3 + (c-64)];
        XsB[r*104 + c] = (unsigned short)bf16u(v);
    }
    __syncthreads();

    const int arow = wv*16 + mrow;
    f32x4 acc0[4];
#pragma unroll
    for (int ct = 0; ct < 4; ++ct) {
        float bv = cb0[ct*16 + mrow];
        acc0[ct] = (f32x4){bv, bv, bv, bv};
    }
#pragma unroll
    for (int kk = 0; kk < 96; kk += 32) {
        bf16x8 a = *(const bf16x8*)(XsB + arow*104 + kk + quad*8);
#pragma unroll
        for (int ct = 0; ct < 4; ++ct) {
            bf16x8 b = *(const bf16x8*)(W0B + (ct*16 + mrow)*104 + kk + quad*8);
            acc0[ct] = __builtin_amdgcn_mfma_f32_16x16x32_bf16(a, b, acc0[ct], 0, 0, 0);
        }
    }

    if constexpr (DEPTH == 1) {
#pragma unroll
        for (int ct = 0; ct < 4; ++ct) {
            f32x4 v = acc0[ct];
            float s = (v.x + v.y) + (v.z + v.w);
            float q = (v.x*v.x + v.y*v.y) + (v.z*v.z + v.w*v.w);
            atomicAdd(&sAcc[ct*16 + mrow], s);
            atomicAdd(&qAcc[ct*16 + mrow], q);
        }
        __syncthreads();
        if (tid < 64) { atomicAdd(statS + tid, sAcc[tid]); atomicAdd(statQ + tid, qAcc[tid]); }
        return;
    } else {
        const int rbase = wv*16 + quad*4;
#pragma unroll
        for (int ct = 0; ct < 4; ++ct) {
            int col = ct*16 + mrow;
            float a = bnab0[col], sh = bnab0[64 + col];
            f32x4 v = acc0[ct];
            Gb[(rbase+0)*72 + col] = (unsigned short)bf16u(fmaxf(fmaf(a, v.x, sh), 0.f));
            Gb[(rbase+1)*72 + col] = (unsigned short)bf16u(fmaxf(fmaf(a, v.y, sh), 0.f));
            Gb[(rbase+2)*72 + col] = (unsigned short)bf16u(fmaxf(fmaf(a, v.z, sh), 0.f));
            Gb[(rbase+3)*72 + col] = (unsigned short)bf16u(fmaxf(fmaf(a, v.w, sh), 0.f));
        }
        f32x4 acc1[4];
#pragma unroll
        for (int ct = 0; ct < 4; ++ct) {
            float bv = cb1[ct*16 + mrow];
            acc1[ct] = (f32x4){bv, bv, bv, bv};
        }
#pragma unroll
        for (int kk = 0; kk < 64; kk += 32) {
            bf16x8 a = *(const bf16x8*)(Gb + arow*72 + kk + quad*8);
#pragma unroll
            for (int ct = 0; ct < 4; ++ct) {
                bf16x8 b = *(const bf16x8*)(W1B + (ct*16 + mrow)*72 + kk + quad*8);
                acc1[ct] = __builtin_amdgcn_mfma_f32_16x16x32_bf16(a, b, acc1[ct], 0, 0, 0);
            }
        }
        if constexpr (DEPTH == 2) {
#pragma unroll
            for (int ct = 0; ct < 4; ++ct) {
                f32x4 v = acc1[ct];
                float s = (v.x + v.y) + (v.z + v.w);
                float q = (v.x*v.x + v.y*v.y) + (v.z*v.z + v.w*v.w);
                atomicAdd(&sAcc[ct*16 + mrow], s);
                atomicAdd(&qAcc[ct*16 + mrow], q);
            }
            __syncthreads();
            if (tid < 64) { atomicAdd(statS + tid, sAcc[tid]); atomicAdd(statQ + tid, qAcc[tid]); }
            return;
        } else {
#pragma unroll
            for (int ct = 0; ct < 4; ++ct) {
                int col = ct*16 + mrow;
                float a = bnab1[col], sh = bnab1[64 + col];
                f32x4 v = acc1[ct];
                Gb[(rbase+0)*72 + col] = (unsigned short)bf16u(fmaxf(fmaf(a, v.x, sh), 0.f));
                Gb[(rbase+1)*72 + col] = (unsigned short)bf16u(fmaxf(fmaf(a, v.y, sh), 0.f));
                Gb[(rbase+2)*72 + col] = (unsigned short)bf16u(fmaxf(fmaf(a, v.z, sh), 0.f));
                Gb[(rbase+3)*72 + col] = (unsigned short)bf16u(fmaxf(fmaf(a, v.w, sh), 0.f));
            }
            f32x4 acc2[8];
#pragma unroll
            for (int ct = 0; ct < 8; ++ct) {
                float bv = cb2[ct*16 + mrow];
                acc2[ct] = (f32x4){bv, bv, bv, bv};
            }
#pragma unroll
            for (int kk = 0; kk < 64; kk += 32) {
                bf16x8 a = *(const bf16x8*)(Gb + arow*72 + kk + quad*8);
#pragma unroll
                for (int ct = 0; ct < 8; ++ct) {
                    bf16x8 b = *(const bf16x8*)(W2B + (ct*16 + mrow)*72 + kk + quad*8);
                    acc2[ct] = __builtin_amdgcn_mfma_f32_16x16x32_bf16(a, b, acc2[ct], 0, 0, 0);
                }
            }
#pragma unroll
            for (int ct = 0; ct < 8; ++ct) {
                f32x4 v = acc2[ct];
                float s = (v.x + v.y) + (v.z + v.w);
                float q = (v.x*v.x + v.y*v.y) + (v.z*v.z + v.w*v.w);
                atomicAdd(&sAcc[ct*16 + mrow], s);
                atomicAdd(&qAcc[ct*16 + mrow], q);
            }
#pragma unroll
            for (int ct = 0; ct < 8; ++ct) {
                f32x4 v = acc2[ct];
                float mx = fmaxf(fmaxf(v.x, v.y), fmaxf(v.z, v.w));
                float mn = fminf(fminf(v.x, v.y), fminf(v.z, v.w));
                { float o = __shfl_xor(mx, 16); mx = fmaxf(mx, o); }
                { float o = __shfl_xor(mn, 16); mn = fminf(mn, o); }
                { float o = __shfl_xor(mx, 32); mx = fmaxf(mx, o); }
                { float o = __shfl_xor(mn, 32); mn = fminf(mn, o); }
                if (quad == 0) {
                    mxs[wv*128 + ct*16 + mrow] = mx;
                    mns[wv*128 + ct*16 + mrow] = mn;
                }
            }
            __syncthreads();
            {
                int g = tid >> 7, c = tid & 127;
                float mx = fmaxf(mxs[(2*g)*128 + c], mxs[(2*g+1)*128 + c]);
                float mn = fminf(mns[(2*g)*128 + c], mns[(2*g+1)*128 + c]);
                packed[(size_t)(blockIdx.x*2 + g)*128 + c] = (bf16u(mx) << 16) | bf16u(mn);
            }
            if (tid < 128) { atomicAdd(statS + tid, sAcc[tid]); atomicAdd(statQ + tid, qAcc[tid]); }
        }
    }
}

// ---------------- BN finalize: direct (fallback) ----------------
template<int COUT>
__global__ void bn_finalize(const float* __restrict__ stat_s, const float* __restrict__ stat_q,
                            const float* __restrict__ gamma, const float* __restrict__ beta,
                            float* __restrict__ bnab) {
    int c = threadIdx.x;
    if (c < COUT) {
        const float inv_n = 1.f / (float)RTOT;
        float mu  = stat_s[c] * inv_n;
        float var = stat_q[c] * inv_n - mu*mu;
        float inv = 1.f / sqrtf(var + EPSF);
        float a = gamma[c] * inv;
        bnab[c] = a;
        bnab[COUT + c] = beta[c] - mu * a;
    }
}

// ---------------- BN finalize: bucketed (fast path) ----------------
template<int COUT>
__global__ void bn_finalize_bk(const float* __restrict__ sb,
                               const float* __restrict__ gamma, const float* __restrict__ beta,
                               float* __restrict__ bnab) {
    int c = threadIdx.x;
    if (c < COUT) {
        float s = 0.f, q = 0.f;
        for (int k = 0; k < 64; ++k) {
            s += sb[k*COUT + c];
            q += sb[64*COUT + k*COUT + c];
        }
        const float inv_n = 1.f / (float)RTOT;
        float mu  = s * inv_n;
        float var = q * inv_n - mu*mu;
        float inv = 1.f / sqrtf(var + EPSF);
        float a = gamma[c] * inv;
        bnab[c] = a;
        bnab[COUT + c] = beta[c] - mu * a;
    }
}

// ---------------- final: BN2+ReLU on pooled extrema ----------------
__global__ __launch_bounds__(256) void final_out(const unsigned int* __restrict__ packed,
                                                 const float* __restrict__ bnab2,
                                                 float* __restrict__ out_np) {
    int idx = blockIdx.x*256 + threadIdx.x;
    int c = idx & 127;
    float a = bnab2[c], sh = bnab2[128 + c];
    unsigned p = packed[idx];
    float mx = __uint_as_float(p & 0xFFFF0000u);
    float mn = __uint_as_float(p << 16);
    float x = (a >= 0.f) ? mx : mn;
    out_np[idx] = fmaxf(fmaf(a, x, sh), 0.f);
}

extern "C" void kernel_launch(void* const* d_in, const int* in_sizes, int n_in,
                              void* d_out, int out_size, void* d_ws, size_t ws_size,
                              hipStream_t stream) {
    const float* xyz    = (const float*)d_in[0];
    const float* points = (const float*)d_in[1];
    const float* W0 = (const float*)d_in[2];
    const float* b0 = (const float*)d_in[3];
    const float* g0 = (const float*)d_in[4];
    const float* be0= (const float*)d_in[5];
    const float* W1 = (const float*)d_in[6];
    const float* b1 = (const float*)d_in[7];
    const float* g1 = (const float*)d_in[8];
    const float* be1= (const float*)d_in[9];
    const float* W2 = (const float*)d_in[10];
    const float* b2 = (const float*)d_in[11];
    const float* g2 = (const float*)d_in[12];
    const float* be2= (const float*)d_in[13];

    float* ws  = (float*)d_ws;
    float* out = (float*)d_out;
    float* out_newxyz = out;                        // 49152
    float* out_np     = out + 49152;                // 2097152
    float* out_fpsidx = out + 49152 + 2097152;      // 16384

    unsigned short* wt0b = (unsigned short*)(ws + WT0B_OFF);
    unsigned short* wt1b = (unsigned short*)(ws + WT1B_OFF);
    unsigned short* wt2b = (unsigned short*)(ws + WT2B_OFF);
    float* s0 = ws + ST_OFF;        float* q0 = s0 + 64;
    float* s1 = q0 + 64;            float* q1 = s1 + 64;
    float* s2 = q1 + 64;            float* q2 = s2 + 128;
    float* bnab0 = ws + BN_OFF;     float* bnab1 = bnab0 + 128;  float* bnab2 = bnab1 + 128;
    float* nxw   = ws + NXW_OFF;
    int*   kidx  = (int*)(ws + KIDX_OFF);
    unsigned int* packed = (unsigned int*)(ws + PK_OFF);
    unsigned short* y0b = (unsigned short*)(ws + Y0B_OFF);
    unsigned short* y1b = (unsigned short*)(ws + Y1B_OFF);
    float* sb0 = ws + SB0_OFF;
    float* sb1 = ws + SB1_OFF;
    float* sb2 = ws + SB2_OFF;

    int fast = (ws_size >= WS_FAST_BYTES) ? 1 : 0;

    prep_kernel<<<1, 256, 0, stream>>>(W0, W1, W2, ws, fast);
    fps_kernel<<<B_, 256, 0, stream>>>(xyz, out_newxyz, out_fpsidx, nxw);
    knn_kernel<<<(B_*M_)/4, 256, 0, stream>>>(xyz, nxw, kidx);

    if (fast) {
        pass0_kernel<<<RTOT/64, 256, 0, stream>>>(xyz, points, nxw, kidx, wt0b, b0, sb0, y0b);
        bn_finalize_bk<64><<<1, 64, 0, stream>>>(sb0, g0, be0, bnab0);
        pass1_kernel<<<RTOT/64, 256, 0, stream>>>(y0b, wt1b, b1, bnab0, sb1, y1b);
        bn_finalize_bk<64><<<1, 64, 0, stream>>>(sb1, g1, be1, bnab1);
        pass2_kernel<<<RTOT/64, 256, 0, stream>>>(y1b, wt2b, b2, bnab1, sb2, packed);
        bn_finalize_bk<128><<<1, 128, 0, stream>>>(sb2, g2, be2, bnab2);
    } else {
        mlp_pass<1><<<RTOT/64, 256, 0, stream>>>(xyz, points, nxw, kidx, wt0b, wt1b, wt2b,
            b0, b1, b2, nullptr, nullptr, s0, q0, nullptr);
        bn_finalize<64><<<1, 64, 0, stream>>>(s0, q0, g0, be0, bnab0);
        mlp_pass<2><<<RTOT/64, 256, 0, stream>>>(xyz, points, nxw, kidx, wt0b, wt1b, wt2b,
            b0, b1, b2, bnab0, nullptr, s1, q1, nullptr);
        bn_finalize<64><<<1, 64, 0, stream>>>(s1, q1, g1, be1, bnab1);
        mlp_pass<3><<<RTOT/64, 256, 0, stream>>>(xyz, points, nxw, kidx, wt0b, wt1b, wt2b,
            b0, b1, b2, bnab0, bnab1, s2, q2, packed);
        bn_finalize<128><<<1, 128, 0, stream>>>(s2, q2, g2, be2, bnab2);
    }

    final_out<<<(B_*M_*128)/256, 256, 0, stream>>>(packed, bnab2, out_np);
}